// Round 10
// baseline (2295.057 us; speedup 1.0000x reference)
//
#include <hip/hip_runtime.h>

#define DH    20       // hidden width
#define BKSC  10       // log2 nodes per COARSE bucket (sort granularity)
#define BKC   1024     // nodes per coarse bucket
#define MAXKC 128      // max coarse buckets (N=100000 -> KC=98)
#define MAXNB 512      // max chunk blocks (E=3.2M/8192 -> 391)
#define BKSF  8        // log2 nodes per FINE bucket (build granularity)
#define BKF   256      // nodes per fine bucket
#define ECAP  10240    // LDS col-staging capacity per fine bucket (avg ~8.2K)
#define CHUNK 8192     // edges per hist/place block

// ---------------- setup kernels ----------------

__global__ void zero_bhist2(int* __restrict__ bhist_d, int* __restrict__ bhist_s) {
    int i = threadIdx.x;
    if (i < MAXKC) { bhist_d[i] = 0; bhist_s[i] = 0; }
}

// one read pass over src+dst; per-block histograms to pbh (global, coalesced)
// + bucket totals via ~98x2 global atomics per block (negligible)
__global__ __launch_bounds__(256) void bucket_hist2(const int* __restrict__ src,
        const int* __restrict__ dst, int* __restrict__ pbh_d,
        int* __restrict__ pbh_s, int* __restrict__ bhist_d,
        int* __restrict__ bhist_s, int E, int K) {
    __shared__ int hd[MAXKC];
    __shared__ int hs[MAXKC];
    for (int i = threadIdx.x; i < K; i += blockDim.x) { hd[i] = 0; hs[i] = 0; }
    __syncthreads();
    int lo = blockIdx.x * CHUNK;
    int hi = lo + CHUNK; if (hi > E) hi = E;
    for (int e = lo + (int)threadIdx.x; e < hi; e += 256) {
        atomicAdd(&hd[__builtin_nontemporal_load(&dst[e]) >> BKSC], 1);
        atomicAdd(&hs[__builtin_nontemporal_load(&src[e]) >> BKSC], 1);
    }
    __syncthreads();
    for (int i = threadIdx.x; i < K; i += blockDim.x) {
        pbh_d[blockIdx.x * MAXKC + i] = hd[i];
        pbh_s[blockIdx.x * MAXKC + i] = hs[i];
        if (hd[i]) atomicAdd(&bhist_d[i], hd[i]);
        if (hs[i]) atomicAdd(&bhist_s[i], hs[i]);
    }
}

// parallel exclusive scan of both bucket-total arrays (K <= 128), single block
__global__ __launch_bounds__(128) void bucket_scan2(
        const int* __restrict__ bhist_d, int* __restrict__ bbase_d,
        int* __restrict__ bcursor_d, const int* __restrict__ bhist_s,
        int* __restrict__ bbase_s, int* __restrict__ bcursor_s, int K) {
    __shared__ int a[MAXKC];
    __shared__ int b[MAXKC];
    int t = threadIdx.x;
    int vd = (t < K) ? bhist_d[t] : 0;
    int vs = (t < K) ? bhist_s[t] : 0;
    a[t] = vd; b[t] = vs;
    __syncthreads();
    for (int off = 1; off < 128; off <<= 1) {
        int x = (t >= off) ? a[t - off] : 0;
        int y = (t >= off) ? b[t - off] : 0;
        __syncthreads();
        a[t] += x; b[t] += y;
        __syncthreads();
    }
    if (t < K) {
        int ed = a[t] - vd, es = b[t] - vs;
        bbase_d[t] = ed; bcursor_d[t] = ed;
        bbase_s[t] = es; bcursor_s[t] = es;
    }
    if (t == K - 1) { bbase_d[K] = a[t]; bbase_s[K] = b[t]; }
}

// one-pass counting place: per-block run reservation via ONE global atomicAdd
// per (block,bucket) using precomputed pbh counts, then scatter with LDS
// cursors. pairs = (src<<10|dst&1023) dst-sorted; ssort = src&1023 src-sorted.
__global__ __launch_bounds__(256) void bucket_place(const int* __restrict__ src,
        const int* __restrict__ dst, const int* __restrict__ pbh_d,
        const int* __restrict__ pbh_s, int* __restrict__ bcursor_d,
        int* __restrict__ bcursor_s, int* __restrict__ pairs,
        int* __restrict__ ssort, int E, int K) {
    __shared__ int cd[MAXKC];
    __shared__ int cs[MAXKC];
    for (int i = threadIdx.x; i < K; i += blockDim.x) {
        int nd = pbh_d[blockIdx.x * MAXKC + i];
        int ns = pbh_s[blockIdx.x * MAXKC + i];
        cd[i] = nd ? atomicAdd(&bcursor_d[i], nd) : 0;
        cs[i] = ns ? atomicAdd(&bcursor_s[i], ns) : 0;
    }
    __syncthreads();
    int lo = blockIdx.x * CHUNK;
    int hi = lo + CHUNK; if (hi > E) hi = E;
    for (int e = lo + (int)threadIdx.x; e < hi; e += 256) {
        int d = __builtin_nontemporal_load(&dst[e]);
        int s = __builtin_nontemporal_load(&src[e]);
        int pd = atomicAdd(&cd[d >> BKSC], 1);          // LDS atomic
        pairs[pd] = (s << BKSC) | (d & (BKC - 1));      // src<2^17 -> 27 bits
        int ps = atomicAdd(&cs[s >> BKSC], 1);
        ssort[ps] = s & (BKC - 1);
    }
}

// per-coarse-src-bucket LDS histogram over its ssort segment -> dout
__global__ __launch_bounds__(256) void bucket_outdeg(const int* __restrict__ bbase_s,
        const int* __restrict__ ssort, double* __restrict__ dout, int n_nodes) {
    __shared__ int h[BKC];
    int k = blockIdx.x;
    int t = threadIdx.x;
    int nbase = k << BKSC;
    int nrem = n_nodes - nbase; if (nrem > BKC) nrem = BKC;
    for (int i = t; i < BKC; i += 256) h[i] = 1;   // self loop
    __syncthreads();
    int e0 = bbase_s[k], e1 = bbase_s[k + 1];
    for (int e = e0 + t; e < e1; e += 256)
        atomicAdd(&h[__builtin_nontemporal_load(&ssort[e])], 1);
    __syncthreads();
    for (int i = t; i < nrem; i += 256)
        dout[nbase + i] = 1.0 / sqrt((double)h[i]);
}

// FINE-granularity build over the COARSE-sorted pairs (unchanged from R8)
__global__ __launch_bounds__(256) void bucket_build(
        const int* __restrict__ bbase, const int* __restrict__ pairs,
        int* __restrict__ row_ptr, double* __restrict__ din,
        int* __restrict__ col, int n_nodes, int n_edges) {
    __shared__ int h[BKF];
    __shared__ int ts[BKF];
    __shared__ int red[256];
    __shared__ int ecol[ECAP];
    int nwg = gridDim.x;
    int xcd = blockIdx.x & 7;
    int loc = blockIdx.x >> 3;
    int q = nwg >> 3, r = nwg & 7;
    int k = ((xcd < r) ? xcd * (q + 1) : r * (q + 1) + (xcd - r) * q) + loc;
    int kc = k >> 2;             // coarse bucket
    int f  = k & 3;              // quarter within coarse bucket
    int t = threadIdx.x;
    int nbase = k << BKSF;
    int nrem = n_nodes - nbase; if (nrem > BKF) nrem = BKF;
    h[t] = 0;
    __syncthreads();
    int e0 = bbase[kc], e1 = bbase[kc + 1];
    int before = 0;
    for (int e = e0 + t; e < e1; e += 256) {
        int pk = pairs[e];
        int dl = pk & (BKC - 1);
        int fe = dl >> BKSF;
        if (fe == f) atomicAdd(&h[dl & (BKF - 1)], 1);
        else if (fe < f) ++before;
    }
    red[t] = before;
    __syncthreads();
    for (int off = 128; off > 0; off >>= 1) {
        if (t < off) red[t] += red[t + off];
        __syncthreads();
    }
    int fbase = e0 + red[0];
    int c = h[t];
    ts[t] = c;
    __syncthreads();
    for (int off = 1; off < 256; off <<= 1) {
        int v = (t >= off) ? ts[t - off] : 0;
        __syncthreads();
        ts[t] += v;
        __syncthreads();
    }
    int lx = ts[t] - c;
    if (t < nrem) {
        row_ptr[nbase + t] = fbase + lx;
        din[nbase + t] = 1.0 / sqrt((double)(c + 1));   // +1 self loop
    }
    h[t] = lx;
    if (t == 0 && nbase + BKF >= n_nodes) row_ptr[n_nodes] = n_edges;
    __syncthreads();
    for (int e = e0 + t; e < e1; e += 256) {
        int pk = pairs[e];
        int dl = pk & (BKC - 1);
        if ((dl >> BKSF) == f) {
            int slot = atomicAdd(&h[dl & (BKF - 1)], 1);
            if (slot < ECAP) ecol[slot] = pk >> BKSC;
            else col[fbase + slot] = pk >> BKSC;
        }
    }
    __syncthreads();
    int cnt = ts[BKF - 1];
    int lim = cnt < ECAP ? cnt : ECAP;
    for (int i = t; i < lim; i += 256)
        col[fbase + i] = ecol[i];
}

// ---------------- layer kernels ----------------

// x0[n] = feat[n] * dout[n]
__global__ void compute_x0(const float* __restrict__ feat, const double* __restrict__ dout,
                           double* __restrict__ x0, int n) {
    int i = blockIdx.x * blockDim.x + threadIdx.x;
    if (i < n) x0[i] = (double)feat[i] * dout[i];
}

// layer 0: g[n] = x0[n] + sum_{s in N(n)} x0[s]
__global__ __launch_bounds__(256) void layer_start(
        const double* __restrict__ x0, const int* __restrict__ row_ptr,
        const int* __restrict__ col, const double* __restrict__ din,
        const double* __restrict__ dout, const float* __restrict__ W,
        const float* __restrict__ b, float* __restrict__ xout, int n_nodes) {
    int n    = (blockIdx.x * blockDim.x + threadIdx.x) >> 6;
    int lane = threadIdx.x & 63;
    if (n >= n_nodes) return;
    double a = (lane == 0) ? x0[n] : 0.0;
    int e0 = row_ptr[n], e1 = row_ptr[n + 1];
    for (int e = e0 + lane; e < e1; e += 64)
        a += x0[__builtin_nontemporal_load(&col[e])];
#pragma unroll
    for (int off = 32; off > 0; off >>= 1)
        a += __shfl_xor(a, off, 64);
    if (lane < DH) {
        double v = a * din[n] * (double)W[lane] + (double)b[lane];
        float r = fmaxf((float)v, 0.0f);
        xout[(long)n * DH + lane] = (float)((double)r * dout[n]);
    }
}

// dense transform: y = h' @ W, written as TWO planes so each gather pass's
// working set fits a 4MB per-XCD L2: y8 = N x 8 floats (3.2MB, feats 0..7),
// y12 = N x 12 floats (4.8MB, feats 8..19).
__global__ __launch_bounds__(256) void transform(
        const float* __restrict__ h, const float* __restrict__ W,
        float4* __restrict__ y8, float4* __restrict__ y12, int n_nodes) {
    __shared__ float Wl[DH * DH];
    for (int i = threadIdx.x; i < DH * DH; i += blockDim.x) Wl[i] = W[i];
    __syncthreads();
    int n = blockIdx.x * blockDim.x + threadIdx.x;
    if (n >= n_nodes) return;
    const float4* h4 = (const float4*)(h + (size_t)n * DH);
    float4 a0 = h4[0], a1 = h4[1], a2 = h4[2], a3 = h4[3], a4 = h4[4];
    float hv[DH] = {a0.x, a0.y, a0.z, a0.w, a1.x, a1.y, a1.z, a1.w,
                    a2.x, a2.y, a2.z, a2.w, a3.x, a3.y, a3.z, a3.w,
                    a4.x, a4.y, a4.z, a4.w};
    double acc[DH];
#pragma unroll
    for (int j = 0; j < DH; ++j) acc[j] = 0.0;
#pragma unroll
    for (int k = 0; k < DH; ++k) {
        double hk = (double)hv[k];
#pragma unroll
        for (int j = 0; j < DH; ++j)
            acc[j] += hk * (double)Wl[k * DH + j];
    }
    y8[n * 2 + 0]  = make_float4((float)acc[0],  (float)acc[1],  (float)acc[2],  (float)acc[3]);
    y8[n * 2 + 1]  = make_float4((float)acc[4],  (float)acc[5],  (float)acc[6],  (float)acc[7]);
    y12[n * 3 + 0] = make_float4((float)acc[8],  (float)acc[9],  (float)acc[10], (float)acc[11]);
    y12[n * 3 + 1] = make_float4((float)acc[12], (float)acc[13], (float)acc[14], (float)acc[15]);
    y12[n * 3 + 2] = make_float4((float)acc[16], (float)acc[17], (float)acc[18], (float)acc[19]);
}

// gather pass 0: features 0..7 from y8 (3.2MB, XCD-L2-resident; 32B rows are
// line-aligned -> 1 line/edge). jq = lane&1 (float4 half), ep = lane>>1
// (32 edge slots), 2 gathers/lane -> 64 edges; tail loop beyond.
__global__ __launch_bounds__(256, 8) void gather8(
        const float4* __restrict__ y8, const int* __restrict__ row_ptr,
        const int* __restrict__ col, const double* __restrict__ din,
        const double* __restrict__ dout, const float* __restrict__ b,
        float* __restrict__ hout, int n_nodes, int mode) {
    int n    = (blockIdx.x * blockDim.x + threadIdx.x) >> 6;
    int lane = threadIdx.x & 63;
    if (n >= n_nodes) return;
    int jq = lane & 1;
    int ep = lane >> 1;          // 32 edge slots

    int e0 = row_ptr[n], e1 = row_ptr[n + 1];
    int s0 = -1, s1 = -1;
    {
        int p = e0 + ep;
        if (p      < e1) s0 = __builtin_nontemporal_load(&col[p]);
        if (p + 32 < e1) s1 = __builtin_nontemporal_load(&col[p + 32]);
    }
    bool p0 = s0 >= 0, p1 = s1 >= 0;
    float4 v0 = y8[(p0 ? s0 : n) * 2 + jq];
    float4 v1 = y8[(p1 ? s1 : n) * 2 + jq];

    double g[4] = {0.0, 0.0, 0.0, 0.0};
    if (ep == 0) {               // self loop
        float4 v = y8[n * 2 + jq];
        g[0] = (double)v.x; g[1] = (double)v.y; g[2] = (double)v.z; g[3] = (double)v.w;
    }
    if (p0) { g[0] += (double)v0.x; g[1] += (double)v0.y; g[2] += (double)v0.z; g[3] += (double)v0.w; }
    if (p1) { g[0] += (double)v1.x; g[1] += (double)v1.y; g[2] += (double)v1.z; g[3] += (double)v1.w; }

    if (e1 - e0 > 64) {          // rare tail (deg > 64), wave-uniform
        for (int e = e0 + 64 + ep; e < e1; e += 32) {
            int s = __builtin_nontemporal_load(&col[e]);
            float4 v = y8[s * 2 + jq];
            g[0] += (double)v.x; g[1] += (double)v.y;
            g[2] += (double)v.z; g[3] += (double)v.w;
        }
    }

    // fold 32 slots -> slot 0 in f32
    float f0 = (float)g[0], f1 = (float)g[1], f2 = (float)g[2], f3 = (float)g[3];
#define FOLD8(LIM, DL)                                                          \
    {                                                                           \
        int srcl = lane + DL; if (srcl > 63) srcl = lane;                       \
        float t0 = __shfl(f0, srcl, 64);                                        \
        float t1 = __shfl(f1, srcl, 64);                                        \
        float t2 = __shfl(f2, srcl, 64);                                        \
        float t3 = __shfl(f3, srcl, 64);                                        \
        if (ep < (LIM)) { f0 += t0; f1 += t1; f2 += t2; f3 += t3; }             \
    }
    FOLD8(16, 32)
    FOLD8(8, 16)
    FOLD8(4, 8)
    FOLD8(2, 4)
    FOLD8(1, 2)
#undef FOLD8

    if (lane < 2) {              // lanes 0,1 hold features jq*4..jq*4+3
        double dn = din[n];
        float4 bb = ((const float4*)b)[jq];
        double o0 = (double)f0 * dn + (double)bb.x;
        double o1 = (double)f1 * dn + (double)bb.y;
        double o2 = (double)f2 * dn + (double)bb.z;
        double o3 = (double)f3 * dn + (double)bb.w;
        float4 w;
        if (mode == 0) {
            double dd = dout[n];
            w.x = (float)((double)fmaxf((float)o0, 0.0f) * dd);
            w.y = (float)((double)fmaxf((float)o1, 0.0f) * dd);
            w.z = (float)((double)fmaxf((float)o2, 0.0f) * dd);
            w.w = (float)((double)fmaxf((float)o3, 0.0f) * dd);
        } else {
            w.x = (float)o0; w.y = (float)o1; w.z = (float)o2; w.w = (float)o3;
        }
        *(float4*)(hout + (size_t)n * DH + jq * 4) = w;
    }
}

// gather pass 1: features 8..19 from y12 (4.8MB, mostly XCD-L2-resident).
// ep = lane/3 (21 edge slots, lane 63 idle), jq = lane-3*ep in {0,1,2},
// 3 gathers/lane -> 63 edges; tail loop beyond.
__global__ __launch_bounds__(256, 8) void gather12(
        const float4* __restrict__ y12, const int* __restrict__ row_ptr,
        const int* __restrict__ col, const double* __restrict__ din,
        const double* __restrict__ dout, const float* __restrict__ b,
        float* __restrict__ hout, int n_nodes, int mode) {
    int n    = (blockIdx.x * blockDim.x + threadIdx.x) >> 6;
    int lane = threadIdx.x & 63;
    if (n >= n_nodes) return;
    int ep = lane / 3;           // 0..21 (ep==21 -> lane 63, inactive)
    int jq = lane - ep * 3;

    int e0 = row_ptr[n], e1 = row_ptr[n + 1];
    int s0 = -1, s1 = -1, s2 = -1;
    if (ep < 21) {
        int p = e0 + ep;
        if (p      < e1) s0 = __builtin_nontemporal_load(&col[p]);
        if (p + 21 < e1) s1 = __builtin_nontemporal_load(&col[p + 21]);
        if (p + 42 < e1) s2 = __builtin_nontemporal_load(&col[p + 42]);
    }
    bool p0 = s0 >= 0, p1 = s1 >= 0, p2 = s2 >= 0;
    float4 v0 = y12[(p0 ? s0 : n) * 3 + jq];
    float4 v1 = y12[(p1 ? s1 : n) * 3 + jq];
    float4 v2 = y12[(p2 ? s2 : n) * 3 + jq];

    double g[4] = {0.0, 0.0, 0.0, 0.0};
    if (ep == 0) {               // self loop
        float4 v = y12[n * 3 + jq];
        g[0] = (double)v.x; g[1] = (double)v.y; g[2] = (double)v.z; g[3] = (double)v.w;
    }
    if (p0) { g[0] += (double)v0.x; g[1] += (double)v0.y; g[2] += (double)v0.z; g[3] += (double)v0.w; }
    if (p1) { g[0] += (double)v1.x; g[1] += (double)v1.y; g[2] += (double)v1.z; g[3] += (double)v1.w; }
    if (p2) { g[0] += (double)v2.x; g[1] += (double)v2.y; g[2] += (double)v2.z; g[3] += (double)v2.w; }

    if (e1 - e0 > 63) {          // rare tail (deg > 63), wave-uniform
        if (ep < 21) {
            for (int e = e0 + 63 + ep; e < e1; e += 21) {
                int s = __builtin_nontemporal_load(&col[e]);
                float4 v = y12[s * 3 + jq];
                g[0] += (double)v.x; g[1] += (double)v.y;
                g[2] += (double)v.z; g[3] += (double)v.w;
            }
        }
    }

    // fold 21 slots -> slot 0 in f32 (deltas in lanes = 3*slot-delta)
    float f0 = (float)g[0], f1 = (float)g[1], f2 = (float)g[2], f3 = (float)g[3];
#define FOLD12(LIM, DL)                                                         \
    {                                                                           \
        int srcl = lane + DL; if (srcl > 63) srcl = lane;                       \
        float t0 = __shfl(f0, srcl, 64);                                        \
        float t1 = __shfl(f1, srcl, 64);                                        \
        float t2 = __shfl(f2, srcl, 64);                                        \
        float t3 = __shfl(f3, srcl, 64);                                        \
        if (ep < (LIM)) { f0 += t0; f1 += t1; f2 += t2; f3 += t3; }             \
    }
    FOLD12(5, 48)    // slots 0..4   += slots 16..20
    FOLD12(8, 24)    // slots 0..7   += slots 8..15
    FOLD12(4, 12)    // slots 0..3   += slots 4..7
    FOLD12(2, 6)     // slots 0..1   += slots 2..3
    FOLD12(1, 3)     // slot 0       += slot 1
#undef FOLD12

    if (lane < 3) {              // lanes 0..2 hold features 8+jq*4 .. 11+jq*4
        double dn = din[n];
        float4 bb = ((const float4*)(b + 8))[jq];
        double o0 = (double)f0 * dn + (double)bb.x;
        double o1 = (double)f1 * dn + (double)bb.y;
        double o2 = (double)f2 * dn + (double)bb.z;
        double o3 = (double)f3 * dn + (double)bb.w;
        float4 w;
        if (mode == 0) {
            double dd = dout[n];
            w.x = (float)((double)fmaxf((float)o0, 0.0f) * dd);
            w.y = (float)((double)fmaxf((float)o1, 0.0f) * dd);
            w.z = (float)((double)fmaxf((float)o2, 0.0f) * dd);
            w.w = (float)((double)fmaxf((float)o3, 0.0f) * dd);
        } else {
            w.x = (float)o0; w.y = (float)o1; w.z = (float)o2; w.w = (float)o3;
        }
        *(float4*)(hout + (size_t)n * DH + 8 + jq * 4) = w;
    }
}

// ---------------- launch ----------------

static inline size_t align256(size_t x) { return (x + 255) & ~(size_t)255; }

extern "C" void kernel_launch(void* const* d_in, const int* in_sizes, int n_in,
                              void* d_out, int out_size, void* d_ws, size_t ws_size,
                              hipStream_t stream) {
    const float* feat    = (const float*)d_in[0];
    const float* W_start = (const float*)d_in[1];
    const float* b_start = (const float*)d_in[2];
    const float* W_mid   = (const float*)d_in[3];
    const float* b_mid   = (const float*)d_in[4];
    const float* W_final = (const float*)d_in[5];
    const float* b_final = (const float*)d_in[6];
    const int*   src     = (const int*)d_in[7];
    const int*   dst     = (const int*)d_in[8];

    const int N = in_sizes[0];              // 100000
    const int E = in_sizes[7];              // 3200000
    const int L = in_sizes[3] / (DH * DH);  // 18 mid layers
    const int KC = (N + BKC - 1) / BKC;     // coarse buckets (98)
    const int KF = (N + BKF - 1) / BKF;     // fine buckets (391)
    const int NB = (E + CHUNK - 1) / CHUNK; // chunk blocks (391)

    // workspace carve-up
    char* p = (char*)d_ws;
    double* dout_d = (double*)p; p += align256(sizeof(double) * N);
    double* din_d  = (double*)p; p += align256(sizeof(double) * N);
    double* x0     = (double*)p; p += align256(sizeof(double) * N);
    int* row_ptr   = (int*)p;    p += align256(sizeof(int) * (N + 1));
    int* bhist_d   = (int*)p;    p += align256(sizeof(int) * (MAXKC + 1));
    int* bhist_s   = (int*)p;    p += align256(sizeof(int) * (MAXKC + 1));
    int* bbase_d   = (int*)p;    p += align256(sizeof(int) * (MAXKC + 1));
    int* bbase_s   = (int*)p;    p += align256(sizeof(int) * (MAXKC + 1));
    int* bcursor_d = (int*)p;    p += align256(sizeof(int) * (MAXKC + 1));
    int* bcursor_s = (int*)p;    p += align256(sizeof(int) * (MAXKC + 1));
    int* pbh_d     = (int*)p;    p += align256(sizeof(int) * MAXNB * MAXKC);
    int* pbh_s     = (int*)p;    p += align256(sizeof(int) * MAXNB * MAXKC);
    int* col       = (int*)p;    p += align256(sizeof(int) * E);
    float* hbuf    = (float*)p;  p += align256(sizeof(float) * N * DH);
    float4* y8     = (float4*)p; p += align256(sizeof(float4) * N * 2);
    float4* y12    = (float4*)p; p += align256(sizeof(float4) * N * 3);
    // pairs (E ints = 12.8MB) overlays hbuf+y8+y12 (16MB); dead before layer_start
    int* pairs = (int*)hbuf;
    // ssort (E ints) aliases col: consumed by bucket_outdeg BEFORE bucket_build
    int* ssort = col;

    const int BT = 256;
    int grid_n  = (N + BT - 1) / BT;
    int grid_nw = (N + 3) / 4;              // 1 wave per node, 4 waves per block

    // ---- graph setup ----
    zero_bhist2<<<1, MAXKC, 0, stream>>>(bhist_d, bhist_s);
    bucket_hist2<<<NB, BT, 0, stream>>>(src, dst, pbh_d, pbh_s,
                                        bhist_d, bhist_s, E, KC);
    bucket_scan2<<<1, 128, 0, stream>>>(bhist_d, bbase_d, bcursor_d,
                                        bhist_s, bbase_s, bcursor_s, KC);
    bucket_place<<<NB, BT, 0, stream>>>(src, dst, pbh_d, pbh_s,
                                        bcursor_d, bcursor_s, pairs, ssort, E, KC);
    bucket_outdeg<<<KC, BT, 0, stream>>>(bbase_s, ssort, dout_d, N);
    bucket_build<<<KF, BT, 0, stream>>>(bbase_d, pairs, row_ptr, din_d, col, N, E);

    // ---- layer 0 (scalar input) ----
    compute_x0<<<grid_n, BT, 0, stream>>>(feat, dout_d, x0, N);
    layer_start<<<grid_nw, BT, 0, stream>>>(x0, row_ptr, col, din_d, dout_d,
                                            W_start, b_start, hbuf, N);

    // ---- 18 mid layers: transform -> two L2-resident gather passes ----
    for (int l = 0; l < L; ++l) {
        transform<<<grid_n, BT, 0, stream>>>(hbuf, W_mid + (size_t)l * DH * DH,
                                             y8, y12, N);
        gather8<<<grid_nw, BT, 0, stream>>>(y8, row_ptr, col, din_d, dout_d,
                                            b_mid + (size_t)l * DH, hbuf, N, 0);
        gather12<<<grid_nw, BT, 0, stream>>>(y12, row_ptr, col, din_d, dout_d,
                                             b_mid + (size_t)l * DH, hbuf, N, 0);
    }

    // ---- final layer: raw store to d_out ----
    transform<<<grid_n, BT, 0, stream>>>(hbuf, W_final, y8, y12, N);
    gather8<<<grid_nw, BT, 0, stream>>>(y8, row_ptr, col, din_d, dout_d,
                                        b_final, (float*)d_out, N, 1);
    gather12<<<grid_nw, BT, 0, stream>>>(y12, row_ptr, col, din_d, dout_d,
                                         b_final, (float*)d_out, N, 1);
}

// Round 11
// 1542.767 us; speedup vs baseline: 1.4876x; 1.4876x over previous
//
#include <hip/hip_runtime.h>

#define DH    20       // hidden width
#define YP    32       // padded y row (floats): 128B = exactly one cache line
#define BKSC  10       // log2 nodes per COARSE bucket (sort granularity)
#define BKC   1024     // nodes per coarse bucket
#define MAXKC 128      // max coarse buckets (N=100000 -> KC=98)
#define MAXNB 512      // max chunk blocks (E=3.2M/8192 -> 391)
#define BKSF  8        // log2 nodes per FINE bucket (build granularity)
#define BKF   256      // nodes per fine bucket
#define ECAP  10240    // LDS col-staging capacity per fine bucket (avg ~8.2K)
#define CHUNK 8192     // edges per hist/place block

// ---------------- setup kernels ----------------

__global__ void zero_bhist2(int* __restrict__ bhist_d, int* __restrict__ bhist_s) {
    int i = threadIdx.x;
    if (i < MAXKC) { bhist_d[i] = 0; bhist_s[i] = 0; }
}

// one read pass over src+dst; per-block histograms to pbh (global, coalesced)
// + bucket totals via ~98x2 global atomics per block (negligible)
__global__ __launch_bounds__(256) void bucket_hist2(const int* __restrict__ src,
        const int* __restrict__ dst, int* __restrict__ pbh_d,
        int* __restrict__ pbh_s, int* __restrict__ bhist_d,
        int* __restrict__ bhist_s, int E, int K) {
    __shared__ int hd[MAXKC];
    __shared__ int hs[MAXKC];
    for (int i = threadIdx.x; i < K; i += blockDim.x) { hd[i] = 0; hs[i] = 0; }
    __syncthreads();
    int lo = blockIdx.x * CHUNK;
    int hi = lo + CHUNK; if (hi > E) hi = E;
    for (int e = lo + (int)threadIdx.x; e < hi; e += 256) {
        atomicAdd(&hd[__builtin_nontemporal_load(&dst[e]) >> BKSC], 1);
        atomicAdd(&hs[__builtin_nontemporal_load(&src[e]) >> BKSC], 1);
    }
    __syncthreads();
    for (int i = threadIdx.x; i < K; i += blockDim.x) {
        pbh_d[blockIdx.x * MAXKC + i] = hd[i];
        pbh_s[blockIdx.x * MAXKC + i] = hs[i];
        if (hd[i]) atomicAdd(&bhist_d[i], hd[i]);
        if (hs[i]) atomicAdd(&bhist_s[i], hs[i]);
    }
}

// parallel exclusive scan of both bucket-total arrays (K <= 128), single block
__global__ __launch_bounds__(128) void bucket_scan2(
        const int* __restrict__ bhist_d, int* __restrict__ bbase_d,
        int* __restrict__ bcursor_d, const int* __restrict__ bhist_s,
        int* __restrict__ bbase_s, int* __restrict__ bcursor_s, int K) {
    __shared__ int a[MAXKC];
    __shared__ int b[MAXKC];
    int t = threadIdx.x;
    int vd = (t < K) ? bhist_d[t] : 0;
    int vs = (t < K) ? bhist_s[t] : 0;
    a[t] = vd; b[t] = vs;
    __syncthreads();
    for (int off = 1; off < 128; off <<= 1) {
        int x = (t >= off) ? a[t - off] : 0;
        int y = (t >= off) ? b[t - off] : 0;
        __syncthreads();
        a[t] += x; b[t] += y;
        __syncthreads();
    }
    if (t < K) {
        int ed = a[t] - vd, es = b[t] - vs;
        bbase_d[t] = ed; bcursor_d[t] = ed;
        bbase_s[t] = es; bcursor_s[t] = es;
    }
    if (t == K - 1) { bbase_d[K] = a[t]; bbase_s[K] = b[t]; }
}

// one-pass counting place: per-block run reservation via ONE global atomicAdd
// per (block,bucket) using precomputed pbh counts, then scatter with LDS
// cursors. pairs = (src<<10|dst&1023) dst-sorted; ssort = src&1023 src-sorted.
__global__ __launch_bounds__(256) void bucket_place(const int* __restrict__ src,
        const int* __restrict__ dst, const int* __restrict__ pbh_d,
        const int* __restrict__ pbh_s, int* __restrict__ bcursor_d,
        int* __restrict__ bcursor_s, int* __restrict__ pairs,
        int* __restrict__ ssort, int E, int K) {
    __shared__ int cd[MAXKC];
    __shared__ int cs[MAXKC];
    for (int i = threadIdx.x; i < K; i += blockDim.x) {
        int nd = pbh_d[blockIdx.x * MAXKC + i];
        int ns = pbh_s[blockIdx.x * MAXKC + i];
        cd[i] = nd ? atomicAdd(&bcursor_d[i], nd) : 0;
        cs[i] = ns ? atomicAdd(&bcursor_s[i], ns) : 0;
    }
    __syncthreads();
    int lo = blockIdx.x * CHUNK;
    int hi = lo + CHUNK; if (hi > E) hi = E;
    for (int e = lo + (int)threadIdx.x; e < hi; e += 256) {
        int d = __builtin_nontemporal_load(&dst[e]);
        int s = __builtin_nontemporal_load(&src[e]);
        int pd = atomicAdd(&cd[d >> BKSC], 1);          // LDS atomic
        pairs[pd] = (s << BKSC) | (d & (BKC - 1));      // src<2^17 -> 27 bits
        int ps = atomicAdd(&cs[s >> BKSC], 1);
        ssort[ps] = s & (BKC - 1);
    }
}

// per-coarse-src-bucket LDS histogram over its ssort segment -> dout (f32,
// computed in f64 then rounded — matches reference power(deg,-0.5) in f32)
__global__ __launch_bounds__(256) void bucket_outdeg(const int* __restrict__ bbase_s,
        const int* __restrict__ ssort, float* __restrict__ dout, int n_nodes) {
    __shared__ int h[BKC];
    int k = blockIdx.x;
    int t = threadIdx.x;
    int nbase = k << BKSC;
    int nrem = n_nodes - nbase; if (nrem > BKC) nrem = BKC;
    for (int i = t; i < BKC; i += 256) h[i] = 1;   // self loop
    __syncthreads();
    int e0 = bbase_s[k], e1 = bbase_s[k + 1];
    for (int e = e0 + t; e < e1; e += 256)
        atomicAdd(&h[__builtin_nontemporal_load(&ssort[e])], 1);
    __syncthreads();
    for (int i = t; i < nrem; i += 256)
        dout[nbase + i] = (float)(1.0 / sqrt((double)h[i]));
}

// FINE-granularity build over the COARSE-sorted pairs (unchanged from R8,
// except din is f32 now)
__global__ __launch_bounds__(256) void bucket_build(
        const int* __restrict__ bbase, const int* __restrict__ pairs,
        int* __restrict__ row_ptr, float* __restrict__ din,
        int* __restrict__ col, int n_nodes, int n_edges) {
    __shared__ int h[BKF];
    __shared__ int ts[BKF];
    __shared__ int red[256];
    __shared__ int ecol[ECAP];
    int nwg = gridDim.x;
    int xcd = blockIdx.x & 7;
    int loc = blockIdx.x >> 3;
    int q = nwg >> 3, r = nwg & 7;
    int k = ((xcd < r) ? xcd * (q + 1) : r * (q + 1) + (xcd - r) * q) + loc;
    int kc = k >> 2;             // coarse bucket
    int f  = k & 3;              // quarter within coarse bucket
    int t = threadIdx.x;
    int nbase = k << BKSF;
    int nrem = n_nodes - nbase; if (nrem > BKF) nrem = BKF;
    h[t] = 0;
    __syncthreads();
    int e0 = bbase[kc], e1 = bbase[kc + 1];
    int before = 0;
    for (int e = e0 + t; e < e1; e += 256) {
        int pk = pairs[e];
        int dl = pk & (BKC - 1);
        int fe = dl >> BKSF;
        if (fe == f) atomicAdd(&h[dl & (BKF - 1)], 1);
        else if (fe < f) ++before;
    }
    red[t] = before;
    __syncthreads();
    for (int off = 128; off > 0; off >>= 1) {
        if (t < off) red[t] += red[t + off];
        __syncthreads();
    }
    int fbase = e0 + red[0];
    int c = h[t];
    ts[t] = c;
    __syncthreads();
    for (int off = 1; off < 256; off <<= 1) {
        int v = (t >= off) ? ts[t - off] : 0;
        __syncthreads();
        ts[t] += v;
        __syncthreads();
    }
    int lx = ts[t] - c;
    if (t < nrem) {
        row_ptr[nbase + t] = fbase + lx;
        din[nbase + t] = (float)(1.0 / sqrt((double)(c + 1)));   // +1 self loop
    }
    h[t] = lx;
    if (t == 0 && nbase + BKF >= n_nodes) row_ptr[n_nodes] = n_edges;
    __syncthreads();
    for (int e = e0 + t; e < e1; e += 256) {
        int pk = pairs[e];
        int dl = pk & (BKC - 1);
        if ((dl >> BKSF) == f) {
            int slot = atomicAdd(&h[dl & (BKF - 1)], 1);
            if (slot < ECAP) ecol[slot] = pk >> BKSC;
            else col[fbase + slot] = pk >> BKSC;
        }
    }
    __syncthreads();
    int cnt = ts[BKF - 1];
    int lim = cnt < ECAP ? cnt : ECAP;
    for (int i = t; i < lim; i += 256)
        col[fbase + i] = ecol[i];
}

// ---------------- layer kernels ----------------

// x0[n] = feat[n] * dout[n]
__global__ void compute_x0(const float* __restrict__ feat, const float* __restrict__ dout,
                           double* __restrict__ x0, int n) {
    int i = blockIdx.x * blockDim.x + threadIdx.x;
    if (i < n) x0[i] = (double)feat[i] * (double)dout[i];
}

// layer 0: g[n] = x0[n] + sum_{s in N(n)} x0[s]
__global__ __launch_bounds__(256) void layer_start(
        const double* __restrict__ x0, const int* __restrict__ row_ptr,
        const int* __restrict__ col, const float* __restrict__ din,
        const float* __restrict__ dout, const float* __restrict__ W,
        const float* __restrict__ b, float* __restrict__ xout, int n_nodes) {
    int n    = (blockIdx.x * blockDim.x + threadIdx.x) >> 6;
    int lane = threadIdx.x & 63;
    if (n >= n_nodes) return;
    double a = (lane == 0) ? x0[n] : 0.0;
    int e0 = row_ptr[n], e1 = row_ptr[n + 1];
    for (int e = e0 + lane; e < e1; e += 64)
        a += x0[__builtin_nontemporal_load(&col[e])];
#pragma unroll
    for (int off = 32; off > 0; off >>= 1)
        a += __shfl_xor(a, off, 64);
    if (lane < DH) {
        double v = a * (double)din[n] * (double)W[lane] + (double)b[lane];
        float r = fmaxf((float)v, 0.0f);
        xout[(long)n * DH + lane] = r * dout[n];
    }
}

// dense transform: y[n] = h'[n] @ W, written to 128B-padded rows (YP=32 floats,
// 20 used) so every gather touches exactly ONE cache line per edge-quarter-set.
__global__ __launch_bounds__(256) void transform(
        const float* __restrict__ h, const float* __restrict__ W,
        float4* __restrict__ y, int n_nodes) {
    __shared__ float Wl[DH * DH];
    for (int i = threadIdx.x; i < DH * DH; i += blockDim.x) Wl[i] = W[i];
    __syncthreads();
    int n = blockIdx.x * blockDim.x + threadIdx.x;
    if (n >= n_nodes) return;
    const float4* h4 = (const float4*)(h + (size_t)n * DH);
    float4 a0 = h4[0], a1 = h4[1], a2 = h4[2], a3 = h4[3], a4 = h4[4];
    float hv[DH] = {a0.x, a0.y, a0.z, a0.w, a1.x, a1.y, a1.z, a1.w,
                    a2.x, a2.y, a2.z, a2.w, a3.x, a3.y, a3.z, a3.w,
                    a4.x, a4.y, a4.z, a4.w};
    double acc[DH];
#pragma unroll
    for (int j = 0; j < DH; ++j) acc[j] = 0.0;
#pragma unroll
    for (int k = 0; k < DH; ++k) {
        double hk = (double)hv[k];
#pragma unroll
        for (int j = 0; j < DH; ++j)
            acc[j] += hk * (double)Wl[k * DH + j];
    }
    float4* yr = y + (size_t)n * (YP / 4);
    yr[0] = make_float4((float)acc[0],  (float)acc[1],  (float)acc[2],  (float)acc[3]);
    yr[1] = make_float4((float)acc[4],  (float)acc[5],  (float)acc[6],  (float)acc[7]);
    yr[2] = make_float4((float)acc[8],  (float)acc[9],  (float)acc[10], (float)acc[11]);
    yr[3] = make_float4((float)acc[12], (float)acc[13], (float)acc[14], (float)acc[15]);
    yr[4] = make_float4((float)acc[16], (float)acc[17], (float)acc[18], (float)acc[19]);
}

// gather+aggregate: h'[n] = relu(din[n]*(y[n] + sum_{s in N(n)} y[s]) + b) * dout[n]
// f32 accumulation throughout (matches reference's f32 segment_sum chain);
// y rows 128B-aligned -> 1 line per edge-row.
__global__ __launch_bounds__(256, 8) void gather_agg(
        const float4* __restrict__ y, const int* __restrict__ row_ptr,
        const int* __restrict__ col, const float* __restrict__ din,
        const float* __restrict__ dout, const float* __restrict__ b,
        float* __restrict__ hout, int n_nodes, int mode) {
    int n    = (blockIdx.x * blockDim.x + threadIdx.x) >> 6;
    int lane = threadIdx.x & 63;
    if (n >= n_nodes) return;

    int ep = lane / 5;           // edge slot 0..12 (lanes 60..63 -> ep=12, inactive)
    int jq = lane - ep * 5;      // float4 quarter 0..4

    int e0 = row_ptr[n], e1 = row_ptr[n + 1];

    int s0 = -1, s1 = -1, s2 = -1, s3 = -1;
    if (ep < 12) {
        int p = e0 + ep;
        if (p      < e1) s0 = __builtin_nontemporal_load(&col[p]);
        if (p + 12 < e1) s1 = __builtin_nontemporal_load(&col[p + 12]);
        if (p + 24 < e1) s2 = __builtin_nontemporal_load(&col[p + 24]);
        if (p + 36 < e1) s3 = __builtin_nontemporal_load(&col[p + 36]);
    }
    bool p0 = s0 >= 0, p1 = s1 >= 0, p2 = s2 >= 0, p3 = s3 >= 0;
    float4 v0 = y[(size_t)(p0 ? s0 : n) * (YP / 4) + jq];
    float4 v1 = y[(size_t)(p1 ? s1 : n) * (YP / 4) + jq];
    float4 v2 = y[(size_t)(p2 ? s2 : n) * (YP / 4) + jq];
    float4 v3 = y[(size_t)(p3 ? s3 : n) * (YP / 4) + jq];

    float g0 = 0.f, g1 = 0.f, g2 = 0.f, g3 = 0.f;
    if (ep == 0) {               // self loop handled by slot 0
        float4 v = y[(size_t)n * (YP / 4) + jq];
        g0 = v.x; g1 = v.y; g2 = v.z; g3 = v.w;
    }
    if (p0) { g0 += v0.x; g1 += v0.y; g2 += v0.z; g3 += v0.w; }
    if (p1) { g0 += v1.x; g1 += v1.y; g2 += v1.z; g3 += v1.w; }
    if (p2) { g0 += v2.x; g1 += v2.y; g2 += v2.z; g3 += v2.w; }
    if (p3) { g0 += v3.x; g1 += v3.y; g2 += v3.z; g3 += v3.w; }

    // rare tail: deg > 48 (wave-uniform branch)
    if (e1 - e0 > 48) {
        if (ep < 12) {
            for (int e = e0 + 48 + ep; e < e1; e += 12) {
                int s = __builtin_nontemporal_load(&col[e]);
                float4 v = y[(size_t)s * (YP / 4) + jq];
                g0 += v.x; g1 += v.y; g2 += v.z; g3 += v.w;
            }
        }
    }

    // fold 12 edge slots down to slot 0 in f32
#define FOLD(LIM, DELTA)                                                        \
    {                                                                           \
        int srcl = lane + DELTA; if (srcl > 63) srcl = lane;                    \
        float t0 = __shfl(g0, srcl, 64);                                        \
        float t1 = __shfl(g1, srcl, 64);                                        \
        float t2 = __shfl(g2, srcl, 64);                                        \
        float t3 = __shfl(g3, srcl, 64);                                        \
        if (ep < (LIM)) { g0 += t0; g1 += t1; g2 += t2; g3 += t3; }             \
    }
    FOLD(4, 40)   // ep(0..3)  += ep+8
    FOLD(4, 20)   // ep(0..3)  += ep+4
    FOLD(2, 10)   // ep(0..1)  += ep+2
    FOLD(1, 5)    // ep(0)     += ep+1
#undef FOLD

    if (lane < 5) {
        float dn = din[n];
        float4 bb = ((const float4*)b)[lane];    // b row is 16B-aligned (80B stride)
        float o0 = g0 * dn + bb.x;
        float o1 = g1 * dn + bb.y;
        float o2 = g2 * dn + bb.z;
        float o3 = g3 * dn + bb.w;
        float4 w;
        if (mode == 0) {
            float dd = dout[n];
            w.x = fmaxf(o0, 0.0f) * dd;
            w.y = fmaxf(o1, 0.0f) * dd;
            w.z = fmaxf(o2, 0.0f) * dd;
            w.w = fmaxf(o3, 0.0f) * dd;
        } else {
            w.x = o0; w.y = o1; w.z = o2; w.w = o3;
        }
        ((float4*)(hout + (size_t)n * DH))[lane] = w;   // 5 lanes x 16B = 80B row
    }
}

// ---------------- launch ----------------

static inline size_t align256(size_t x) { return (x + 255) & ~(size_t)255; }

extern "C" void kernel_launch(void* const* d_in, const int* in_sizes, int n_in,
                              void* d_out, int out_size, void* d_ws, size_t ws_size,
                              hipStream_t stream) {
    const float* feat    = (const float*)d_in[0];
    const float* W_start = (const float*)d_in[1];
    const float* b_start = (const float*)d_in[2];
    const float* W_mid   = (const float*)d_in[3];
    const float* b_mid   = (const float*)d_in[4];
    const float* W_final = (const float*)d_in[5];
    const float* b_final = (const float*)d_in[6];
    const int*   src     = (const int*)d_in[7];
    const int*   dst     = (const int*)d_in[8];

    const int N = in_sizes[0];              // 100000
    const int E = in_sizes[7];              // 3200000
    const int L = in_sizes[3] / (DH * DH);  // 18 mid layers
    const int KC = (N + BKC - 1) / BKC;     // coarse buckets (98)
    const int KF = (N + BKF - 1) / BKF;     // fine buckets (391)
    const int NB = (E + CHUNK - 1) / CHUNK; // chunk blocks (391)

    // workspace carve-up
    char* p = (char*)d_ws;
    float* dout_f  = (float*)p;  p += align256(sizeof(float) * N);
    float* din_f   = (float*)p;  p += align256(sizeof(float) * N);
    double* x0     = (double*)p; p += align256(sizeof(double) * N);
    int* row_ptr   = (int*)p;    p += align256(sizeof(int) * (N + 1));
    int* bhist_d   = (int*)p;    p += align256(sizeof(int) * (MAXKC + 1));
    int* bhist_s   = (int*)p;    p += align256(sizeof(int) * (MAXKC + 1));
    int* bbase_d   = (int*)p;    p += align256(sizeof(int) * (MAXKC + 1));
    int* bbase_s   = (int*)p;    p += align256(sizeof(int) * (MAXKC + 1));
    int* bcursor_d = (int*)p;    p += align256(sizeof(int) * (MAXKC + 1));
    int* bcursor_s = (int*)p;    p += align256(sizeof(int) * (MAXKC + 1));
    int* pbh_d     = (int*)p;    p += align256(sizeof(int) * MAXNB * MAXKC);
    int* pbh_s     = (int*)p;    p += align256(sizeof(int) * MAXNB * MAXKC);
    int* col       = (int*)p;    p += align256(sizeof(int) * E);
    float* hbuf    = (float*)p;  p += align256(sizeof(float) * N * DH);
    float4* ypad   = (float4*)p; p += align256(sizeof(float) * N * YP);
    // pairs (E ints = 12.8MB) overlays hbuf+ypad (20.8MB); dead before layer_start
    int* pairs = (int*)hbuf;
    // ssort (E ints) aliases col: consumed by bucket_outdeg BEFORE bucket_build
    int* ssort = col;

    const int BT = 256;
    int grid_n  = (N + BT - 1) / BT;
    int grid_nw = (N + 3) / 4;              // 1 wave per node, 4 waves per block

    // ---- graph setup ----
    zero_bhist2<<<1, MAXKC, 0, stream>>>(bhist_d, bhist_s);
    bucket_hist2<<<NB, BT, 0, stream>>>(src, dst, pbh_d, pbh_s,
                                        bhist_d, bhist_s, E, KC);
    bucket_scan2<<<1, 128, 0, stream>>>(bhist_d, bbase_d, bcursor_d,
                                        bhist_s, bbase_s, bcursor_s, KC);
    bucket_place<<<NB, BT, 0, stream>>>(src, dst, pbh_d, pbh_s,
                                        bcursor_d, bcursor_s, pairs, ssort, E, KC);
    bucket_outdeg<<<KC, BT, 0, stream>>>(bbase_s, ssort, dout_f, N);
    bucket_build<<<KF, BT, 0, stream>>>(bbase_d, pairs, row_ptr, din_f, col, N, E);

    // ---- layer 0 (scalar input) ----
    compute_x0<<<grid_n, BT, 0, stream>>>(feat, dout_f, x0, N);
    layer_start<<<grid_nw, BT, 0, stream>>>(x0, row_ptr, col, din_f, dout_f,
                                            W_start, b_start, hbuf, N);

    // ---- 18 mid layers: dense transform + gather-aggregate ----
    for (int l = 0; l < L; ++l) {
        transform<<<grid_n, BT, 0, stream>>>(hbuf, W_mid + (size_t)l * DH * DH, ypad, N);
        gather_agg<<<grid_nw, BT, 0, stream>>>(ypad, row_ptr, col, din_f, dout_f,
                                               b_mid + (size_t)l * DH, hbuf, N, 0);
    }

    // ---- final layer: raw store to d_out ----
    transform<<<grid_n, BT, 0, stream>>>(hbuf, W_final, ypad, N);
    gather_agg<<<grid_nw, BT, 0, stream>>>(ypad, row_ptr, col, din_f, dout_f,
                                           b_final, (float*)d_out, N, 1);
}

// Round 12
// 1484.582 us; speedup vs baseline: 1.5459x; 1.0392x over previous
//
#include <hip/hip_runtime.h>

#define DH    20       // hidden width
#define YP    32       // padded y row (floats): 128B = exactly one cache line
#define BKSC  10       // log2 nodes per COARSE bucket (sort granularity)
#define BKC   1024     // nodes per coarse bucket
#define MAXKC 128      // max coarse buckets (N=100000 -> KC=98)
#define MAXNB 512      // max chunk blocks (E=3.2M/8192 -> 391)
#define BKSF  8        // log2 nodes per FINE bucket (build granularity)
#define BKF   256      // nodes per fine bucket
#define ECAP  10240    // LDS col-staging capacity per fine bucket (avg ~8.2K)
#define CHUNK 8192     // edges per hist/place block

// ---------------- setup kernels ----------------

__global__ void zero_bhist2(int* __restrict__ bhist_d, int* __restrict__ bhist_s) {
    int i = threadIdx.x;
    if (i < MAXKC) { bhist_d[i] = 0; bhist_s[i] = 0; }
}

// one read pass over src+dst; per-block histograms to pbh (global, coalesced)
// + bucket totals via ~98x2 global atomics per block (negligible)
__global__ __launch_bounds__(256) void bucket_hist2(const int* __restrict__ src,
        const int* __restrict__ dst, int* __restrict__ pbh_d,
        int* __restrict__ pbh_s, int* __restrict__ bhist_d,
        int* __restrict__ bhist_s, int E, int K) {
    __shared__ int hd[MAXKC];
    __shared__ int hs[MAXKC];
    for (int i = threadIdx.x; i < K; i += blockDim.x) { hd[i] = 0; hs[i] = 0; }
    __syncthreads();
    int lo = blockIdx.x * CHUNK;
    int hi = lo + CHUNK; if (hi > E) hi = E;
    for (int e = lo + (int)threadIdx.x; e < hi; e += 256) {
        atomicAdd(&hd[__builtin_nontemporal_load(&dst[e]) >> BKSC], 1);
        atomicAdd(&hs[__builtin_nontemporal_load(&src[e]) >> BKSC], 1);
    }
    __syncthreads();
    for (int i = threadIdx.x; i < K; i += blockDim.x) {
        pbh_d[blockIdx.x * MAXKC + i] = hd[i];
        pbh_s[blockIdx.x * MAXKC + i] = hs[i];
        if (hd[i]) atomicAdd(&bhist_d[i], hd[i]);
        if (hs[i]) atomicAdd(&bhist_s[i], hs[i]);
    }
}

// parallel exclusive scan of both bucket-total arrays (K <= 128), single block
__global__ __launch_bounds__(128) void bucket_scan2(
        const int* __restrict__ bhist_d, int* __restrict__ bbase_d,
        int* __restrict__ bcursor_d, const int* __restrict__ bhist_s,
        int* __restrict__ bbase_s, int* __restrict__ bcursor_s, int K) {
    __shared__ int a[MAXKC];
    __shared__ int b[MAXKC];
    int t = threadIdx.x;
    int vd = (t < K) ? bhist_d[t] : 0;
    int vs = (t < K) ? bhist_s[t] : 0;
    a[t] = vd; b[t] = vs;
    __syncthreads();
    for (int off = 1; off < 128; off <<= 1) {
        int x = (t >= off) ? a[t - off] : 0;
        int y = (t >= off) ? b[t - off] : 0;
        __syncthreads();
        a[t] += x; b[t] += y;
        __syncthreads();
    }
    if (t < K) {
        int ed = a[t] - vd, es = b[t] - vs;
        bbase_d[t] = ed; bcursor_d[t] = ed;
        bbase_s[t] = es; bcursor_s[t] = es;
    }
    if (t == K - 1) { bbase_d[K] = a[t]; bbase_s[K] = b[t]; }
}

// one-pass counting place: per-block run reservation via ONE global atomicAdd
// per (block,bucket) using precomputed pbh counts, then scatter with LDS
// cursors. pairs = (src<<10|dst&1023) dst-sorted; ssort = src&1023 src-sorted.
__global__ __launch_bounds__(256) void bucket_place(const int* __restrict__ src,
        const int* __restrict__ dst, const int* __restrict__ pbh_d,
        const int* __restrict__ pbh_s, int* __restrict__ bcursor_d,
        int* __restrict__ bcursor_s, int* __restrict__ pairs,
        int* __restrict__ ssort, int E, int K) {
    __shared__ int cd[MAXKC];
    __shared__ int cs[MAXKC];
    for (int i = threadIdx.x; i < K; i += blockDim.x) {
        int nd = pbh_d[blockIdx.x * MAXKC + i];
        int ns = pbh_s[blockIdx.x * MAXKC + i];
        cd[i] = nd ? atomicAdd(&bcursor_d[i], nd) : 0;
        cs[i] = ns ? atomicAdd(&bcursor_s[i], ns) : 0;
    }
    __syncthreads();
    int lo = blockIdx.x * CHUNK;
    int hi = lo + CHUNK; if (hi > E) hi = E;
    for (int e = lo + (int)threadIdx.x; e < hi; e += 256) {
        int d = __builtin_nontemporal_load(&dst[e]);
        int s = __builtin_nontemporal_load(&src[e]);
        int pd = atomicAdd(&cd[d >> BKSC], 1);          // LDS atomic
        pairs[pd] = (s << BKSC) | (d & (BKC - 1));      // src<2^17 -> 27 bits
        int ps = atomicAdd(&cs[s >> BKSC], 1);
        ssort[ps] = s & (BKC - 1);
    }
}

// per-coarse-src-bucket LDS histogram over its ssort segment -> dout (f32).
// 1024 threads: h[] maps 1:1 to threads; edge loop ~32 iterations.
__global__ __launch_bounds__(1024) void bucket_outdeg(const int* __restrict__ bbase_s,
        const int* __restrict__ ssort, float* __restrict__ dout, int n_nodes) {
    __shared__ int h[BKC];
    int k = blockIdx.x;
    int t = threadIdx.x;
    int nbase = k << BKSC;
    int nrem = n_nodes - nbase; if (nrem > BKC) nrem = BKC;
    h[t] = 1;                                // self loop
    __syncthreads();
    int e0 = bbase_s[k], e1 = bbase_s[k + 1];
    for (int e = e0 + t; e < e1; e += 1024)
        atomicAdd(&h[__builtin_nontemporal_load(&ssort[e])], 1);
    __syncthreads();
    if (t < nrem) dout[nbase + t] = (float)(1.0 / sqrt((double)h[t]));
}

// FINE-granularity build over the COARSE-sorted pairs. 512 threads (vs 256):
// halves the two serial edge loops (~64 iters each) that made this kernel
// latency-bound at 15% occupancy / 7.4% VALUBusy.
__global__ __launch_bounds__(512) void bucket_build(
        const int* __restrict__ bbase, const int* __restrict__ pairs,
        int* __restrict__ row_ptr, float* __restrict__ din,
        int* __restrict__ col, int n_nodes, int n_edges) {
    __shared__ int h[BKF];
    __shared__ int ts[BKF];
    __shared__ int red[512];
    __shared__ int ecol[ECAP];
    int nwg = gridDim.x;
    int xcd = blockIdx.x & 7;
    int loc = blockIdx.x >> 3;
    int q = nwg >> 3, r = nwg & 7;
    int k = ((xcd < r) ? xcd * (q + 1) : r * (q + 1) + (xcd - r) * q) + loc;
    int kc = k >> 2;             // coarse bucket
    int f  = k & 3;              // quarter within coarse bucket
    int t = threadIdx.x;
    int nbase = k << BKSF;
    int nrem = n_nodes - nbase; if (nrem > BKF) nrem = BKF;
    if (t < BKF) h[t] = 0;
    __syncthreads();
    int e0 = bbase[kc], e1 = bbase[kc + 1];
    int before = 0;
    for (int e = e0 + t; e < e1; e += 512) {
        int pk = pairs[e];                    // plain load: keep L2-cached for siblings
        int dl = pk & (BKC - 1);
        int fe = dl >> BKSF;
        if (fe == f) atomicAdd(&h[dl & (BKF - 1)], 1);
        else if (fe < f) ++before;
    }
    red[t] = before;
    __syncthreads();
    for (int off = 256; off > 0; off >>= 1) {
        if (t < off) red[t] += red[t + off];
        __syncthreads();
    }
    int fbase = e0 + red[0];                  // global base of this fine segment
    int c = (t < BKF) ? h[t] : 0;
    if (t < BKF) ts[t] = c;
    __syncthreads();
    for (int off = 1; off < BKF; off <<= 1) {
        int v = (t >= off && t < BKF) ? ts[t - off] : 0;
        __syncthreads();
        if (t < BKF) ts[t] += v;
        __syncthreads();
    }
    if (t < BKF) {
        int lx = ts[t] - c;                   // fine-local exclusive prefix
        if (t < nrem) {
            row_ptr[nbase + t] = fbase + lx;
            din[nbase + t] = (float)(1.0 / sqrt((double)(c + 1)));  // +1 self loop
        }
        h[t] = lx;                            // fine-local cursor into ecol
    }
    if (t == 0 && nbase + BKF >= n_nodes) row_ptr[n_nodes] = n_edges;
    __syncthreads();
    for (int e = e0 + t; e < e1; e += 512) {
        int pk = pairs[e];
        int dl = pk & (BKC - 1);
        if ((dl >> BKSF) == f) {
            int slot = atomicAdd(&h[dl & (BKF - 1)], 1);    // LDS atomic
            if (slot < ECAP) ecol[slot] = pk >> BKSC;
            else col[fbase + slot] = pk >> BKSC;            // overflow guard
        }
    }
    __syncthreads();
    int cnt = ts[BKF - 1];
    int lim = cnt < ECAP ? cnt : ECAP;
    for (int i = t; i < lim; i += 512)        // contiguous full-line stream-out
        col[fbase + i] = ecol[i];
}

// ---------------- layer kernels ----------------

// x0[n] = feat[n] * dout[n]
__global__ void compute_x0(const float* __restrict__ feat, const float* __restrict__ dout,
                           double* __restrict__ x0, int n) {
    int i = blockIdx.x * blockDim.x + threadIdx.x;
    if (i < n) x0[i] = (double)feat[i] * (double)dout[i];
}

// layer 0: g[n] = x0[n] + sum_{s in N(n)} x0[s]
__global__ __launch_bounds__(256) void layer_start(
        const double* __restrict__ x0, const int* __restrict__ row_ptr,
        const int* __restrict__ col, const float* __restrict__ din,
        const float* __restrict__ dout, const float* __restrict__ W,
        const float* __restrict__ b, float* __restrict__ xout, int n_nodes) {
    int n    = (blockIdx.x * blockDim.x + threadIdx.x) >> 6;
    int lane = threadIdx.x & 63;
    if (n >= n_nodes) return;
    double a = (lane == 0) ? x0[n] : 0.0;
    int e0 = row_ptr[n], e1 = row_ptr[n + 1];
    for (int e = e0 + lane; e < e1; e += 64)
        a += x0[__builtin_nontemporal_load(&col[e])];
#pragma unroll
    for (int off = 32; off > 0; off >>= 1)
        a += __shfl_xor(a, off, 64);
    if (lane < DH) {
        double v = a * (double)din[n] * (double)W[lane] + (double)b[lane];
        float r = fmaxf((float)v, 0.0f);
        xout[(long)n * DH + lane] = r * dout[n];
    }
}

// dense transform: y[n] = h'[n] @ W, written to 128B-padded rows (YP=32 floats,
// 20 used) so every gather touches exactly ONE cache line per edge-quarter-set.
__global__ __launch_bounds__(256) void transform(
        const float* __restrict__ h, const float* __restrict__ W,
        float4* __restrict__ y, int n_nodes) {
    __shared__ float Wl[DH * DH];
    for (int i = threadIdx.x; i < DH * DH; i += blockDim.x) Wl[i] = W[i];
    __syncthreads();
    int n = blockIdx.x * blockDim.x + threadIdx.x;
    if (n >= n_nodes) return;
    const float4* h4 = (const float4*)(h + (size_t)n * DH);
    float4 a0 = h4[0], a1 = h4[1], a2 = h4[2], a3 = h4[3], a4 = h4[4];
    float hv[DH] = {a0.x, a0.y, a0.z, a0.w, a1.x, a1.y, a1.z, a1.w,
                    a2.x, a2.y, a2.z, a2.w, a3.x, a3.y, a3.z, a3.w,
                    a4.x, a4.y, a4.z, a4.w};
    double acc[DH];
#pragma unroll
    for (int j = 0; j < DH; ++j) acc[j] = 0.0;
#pragma unroll
    for (int k = 0; k < DH; ++k) {
        double hk = (double)hv[k];
#pragma unroll
        for (int j = 0; j < DH; ++j)
            acc[j] += hk * (double)Wl[k * DH + j];
    }
    float4* yr = y + (size_t)n * (YP / 4);
    yr[0] = make_float4((float)acc[0],  (float)acc[1],  (float)acc[2],  (float)acc[3]);
    yr[1] = make_float4((float)acc[4],  (float)acc[5],  (float)acc[6],  (float)acc[7]);
    yr[2] = make_float4((float)acc[8],  (float)acc[9],  (float)acc[10], (float)acc[11]);
    yr[3] = make_float4((float)acc[12], (float)acc[13], (float)acc[14], (float)acc[15]);
    yr[4] = make_float4((float)acc[16], (float)acc[17], (float)acc[18], (float)acc[19]);
}

// gather+aggregate: h'[n] = relu(din[n]*(y[n] + sum_{s in N(n)} y[s]) + b) * dout[n]
// f32 accumulation throughout (matches reference's f32 segment_sum chain);
// y rows 128B-aligned -> 1 line per edge-row.
__global__ __launch_bounds__(256, 8) void gather_agg(
        const float4* __restrict__ y, const int* __restrict__ row_ptr,
        const int* __restrict__ col, const float* __restrict__ din,
        const float* __restrict__ dout, const float* __restrict__ b,
        float* __restrict__ hout, int n_nodes, int mode) {
    int n    = (blockIdx.x * blockDim.x + threadIdx.x) >> 6;
    int lane = threadIdx.x & 63;
    if (n >= n_nodes) return;

    int ep = lane / 5;           // edge slot 0..12 (lanes 60..63 -> ep=12, inactive)
    int jq = lane - ep * 5;      // float4 quarter 0..4

    int e0 = row_ptr[n], e1 = row_ptr[n + 1];

    int s0 = -1, s1 = -1, s2 = -1, s3 = -1;
    if (ep < 12) {
        int p = e0 + ep;
        if (p      < e1) s0 = __builtin_nontemporal_load(&col[p]);
        if (p + 12 < e1) s1 = __builtin_nontemporal_load(&col[p + 12]);
        if (p + 24 < e1) s2 = __builtin_nontemporal_load(&col[p + 24]);
        if (p + 36 < e1) s3 = __builtin_nontemporal_load(&col[p + 36]);
    }
    bool p0 = s0 >= 0, p1 = s1 >= 0, p2 = s2 >= 0, p3 = s3 >= 0;
    float4 v0 = y[(size_t)(p0 ? s0 : n) * (YP / 4) + jq];
    float4 v1 = y[(size_t)(p1 ? s1 : n) * (YP / 4) + jq];
    float4 v2 = y[(size_t)(p2 ? s2 : n) * (YP / 4) + jq];
    float4 v3 = y[(size_t)(p3 ? s3 : n) * (YP / 4) + jq];

    float g0 = 0.f, g1 = 0.f, g2 = 0.f, g3 = 0.f;
    if (ep == 0) {               // self loop handled by slot 0
        float4 v = y[(size_t)n * (YP / 4) + jq];
        g0 = v.x; g1 = v.y; g2 = v.z; g3 = v.w;
    }
    if (p0) { g0 += v0.x; g1 += v0.y; g2 += v0.z; g3 += v0.w; }
    if (p1) { g0 += v1.x; g1 += v1.y; g2 += v1.z; g3 += v1.w; }
    if (p2) { g0 += v2.x; g1 += v2.y; g2 += v2.z; g3 += v2.w; }
    if (p3) { g0 += v3.x; g1 += v3.y; g2 += v3.z; g3 += v3.w; }

    // rare tail: deg > 48 (wave-uniform branch)
    if (e1 - e0 > 48) {
        if (ep < 12) {
            for (int e = e0 + 48 + ep; e < e1; e += 12) {
                int s = __builtin_nontemporal_load(&col[e]);
                float4 v = y[(size_t)s * (YP / 4) + jq];
                g0 += v.x; g1 += v.y; g2 += v.z; g3 += v.w;
            }
        }
    }

    // fold 12 edge slots down to slot 0 in f32
#define FOLD(LIM, DELTA)                                                        \
    {                                                                           \
        int srcl = lane + DELTA; if (srcl > 63) srcl = lane;                    \
        float t0 = __shfl(g0, srcl, 64);                                        \
        float t1 = __shfl(g1, srcl, 64);                                        \
        float t2 = __shfl(g2, srcl, 64);                                        \
        float t3 = __shfl(g3, srcl, 64);                                        \
        if (ep < (LIM)) { g0 += t0; g1 += t1; g2 += t2; g3 += t3; }             \
    }
    FOLD(4, 40)   // ep(0..3)  += ep+8
    FOLD(4, 20)   // ep(0..3)  += ep+4
    FOLD(2, 10)   // ep(0..1)  += ep+2
    FOLD(1, 5)    // ep(0)     += ep+1
#undef FOLD

    if (lane < 5) {
        float dn = din[n];
        float4 bb = ((const float4*)b)[lane];    // b row is 16B-aligned (80B stride)
        float o0 = g0 * dn + bb.x;
        float o1 = g1 * dn + bb.y;
        float o2 = g2 * dn + bb.z;
        float o3 = g3 * dn + bb.w;
        float4 w;
        if (mode == 0) {
            float dd = dout[n];
            w.x = fmaxf(o0, 0.0f) * dd;
            w.y = fmaxf(o1, 0.0f) * dd;
            w.z = fmaxf(o2, 0.0f) * dd;
            w.w = fmaxf(o3, 0.0f) * dd;
        } else {
            w.x = o0; w.y = o1; w.z = o2; w.w = o3;
        }
        ((float4*)(hout + (size_t)n * DH))[lane] = w;   // 5 lanes x 16B = 80B row
    }
}

// ---------------- launch ----------------

static inline size_t align256(size_t x) { return (x + 255) & ~(size_t)255; }

extern "C" void kernel_launch(void* const* d_in, const int* in_sizes, int n_in,
                              void* d_out, int out_size, void* d_ws, size_t ws_size,
                              hipStream_t stream) {
    const float* feat    = (const float*)d_in[0];
    const float* W_start = (const float*)d_in[1];
    const float* b_start = (const float*)d_in[2];
    const float* W_mid   = (const float*)d_in[3];
    const float* b_mid   = (const float*)d_in[4];
    const float* W_final = (const float*)d_in[5];
    const float* b_final = (const float*)d_in[6];
    const int*   src     = (const int*)d_in[7];
    const int*   dst     = (const int*)d_in[8];

    const int N = in_sizes[0];              // 100000
    const int E = in_sizes[7];              // 3200000
    const int L = in_sizes[3] / (DH * DH);  // 18 mid layers
    const int KC = (N + BKC - 1) / BKC;     // coarse buckets (98)
    const int KF = (N + BKF - 1) / BKF;     // fine buckets (391)
    const int NB = (E + CHUNK - 1) / CHUNK; // chunk blocks (391)

    // workspace carve-up
    char* p = (char*)d_ws;
    float* dout_f  = (float*)p;  p += align256(sizeof(float) * N);
    float* din_f   = (float*)p;  p += align256(sizeof(float) * N);
    double* x0     = (double*)p; p += align256(sizeof(double) * N);
    int* row_ptr   = (int*)p;    p += align256(sizeof(int) * (N + 1));
    int* bhist_d   = (int*)p;    p += align256(sizeof(int) * (MAXKC + 1));
    int* bhist_s   = (int*)p;    p += align256(sizeof(int) * (MAXKC + 1));
    int* bbase_d   = (int*)p;    p += align256(sizeof(int) * (MAXKC + 1));
    int* bbase_s   = (int*)p;    p += align256(sizeof(int) * (MAXKC + 1));
    int* bcursor_d = (int*)p;    p += align256(sizeof(int) * (MAXKC + 1));
    int* bcursor_s = (int*)p;    p += align256(sizeof(int) * (MAXKC + 1));
    int* pbh_d     = (int*)p;    p += align256(sizeof(int) * MAXNB * MAXKC);
    int* pbh_s     = (int*)p;    p += align256(sizeof(int) * MAXNB * MAXKC);
    int* col       = (int*)p;    p += align256(sizeof(int) * E);
    float* hbuf    = (float*)p;  p += align256(sizeof(float) * N * DH);
    float4* ypad   = (float4*)p; p += align256(sizeof(float) * N * YP);
    // pairs (E ints = 12.8MB) overlays hbuf+ypad (20.8MB); dead before layer_start
    int* pairs = (int*)hbuf;
    // ssort (E ints) aliases col: consumed by bucket_outdeg BEFORE bucket_build
    int* ssort = col;

    const int BT = 256;
    int grid_n  = (N + BT - 1) / BT;
    int grid_nw = (N + 3) / 4;              // 1 wave per node, 4 waves per block

    // ---- graph setup ----
    zero_bhist2<<<1, MAXKC, 0, stream>>>(bhist_d, bhist_s);
    bucket_hist2<<<NB, BT, 0, stream>>>(src, dst, pbh_d, pbh_s,
                                        bhist_d, bhist_s, E, KC);
    bucket_scan2<<<1, 128, 0, stream>>>(bhist_d, bbase_d, bcursor_d,
                                        bhist_s, bbase_s, bcursor_s, KC);
    bucket_place<<<NB, BT, 0, stream>>>(src, dst, pbh_d, pbh_s,
                                        bcursor_d, bcursor_s, pairs, ssort, E, KC);
    bucket_outdeg<<<KC, 1024, 0, stream>>>(bbase_s, ssort, dout_f, N);
    bucket_build<<<KF, 512, 0, stream>>>(bbase_d, pairs, row_ptr, din_f, col, N, E);

    // ---- layer 0 (scalar input) ----
    compute_x0<<<grid_n, BT, 0, stream>>>(feat, dout_f, x0, N);
    layer_start<<<grid_nw, BT, 0, stream>>>(x0, row_ptr, col, din_f, dout_f,
                                            W_start, b_start, hbuf, N);

    // ---- 18 mid layers: dense transform + gather-aggregate ----
    for (int l = 0; l < L; ++l) {
        transform<<<grid_n, BT, 0, stream>>>(hbuf, W_mid + (size_t)l * DH * DH, ypad, N);
        gather_agg<<<grid_nw, BT, 0, stream>>>(ypad, row_ptr, col, din_f, dout_f,
                                               b_mid + (size_t)l * DH, hbuf, N, 0);
    }

    // ---- final layer: raw store to d_out ----
    transform<<<grid_n, BT, 0, stream>>>(hbuf, W_final, ypad, N);
    gather_agg<<<grid_nw, BT, 0, stream>>>(ypad, row_ptr, col, din_f, dout_f,
                                           b_final, (float*)d_out, N, 1);
}

// Round 13
// 1464.020 us; speedup vs baseline: 1.5676x; 1.0140x over previous
//
#include <hip/hip_runtime.h>

#define DH    20       // hidden width
#define YP    32       // padded y row (floats): 128B = exactly one cache line
#define BKSC  10       // log2 nodes per COARSE bucket (sort granularity)
#define BKC   1024     // nodes per coarse bucket
#define MAXKC 128      // max coarse buckets (N=100000 -> KC=98)
#define MAXNB 1024     // max chunk blocks (E=3.2M/4096 -> 782)
#define BKSF  8        // log2 nodes per FINE bucket (build granularity)
#define BKF   256      // nodes per fine bucket
#define ECAP  10240    // LDS col-staging capacity per fine bucket (avg ~8.2K)
#define CHUNK 4096     // edges per hist/place block (782 blocks ~3/CU)

// ---------------- setup kernels ----------------

__global__ void zero_bhist2(int* __restrict__ bhist_d, int* __restrict__ bhist_s) {
    int i = threadIdx.x;
    if (i < MAXKC) { bhist_d[i] = 0; bhist_s[i] = 0; }
}

// one read pass over src+dst; per-block histograms to pbh (global, coalesced)
// + bucket totals via ~98x2 global atomics per block (negligible)
__global__ __launch_bounds__(256) void bucket_hist2(const int* __restrict__ src,
        const int* __restrict__ dst, int* __restrict__ pbh_d,
        int* __restrict__ pbh_s, int* __restrict__ bhist_d,
        int* __restrict__ bhist_s, int E, int K) {
    __shared__ int hd[MAXKC];
    __shared__ int hs[MAXKC];
    for (int i = threadIdx.x; i < K; i += blockDim.x) { hd[i] = 0; hs[i] = 0; }
    __syncthreads();
    int lo = blockIdx.x * CHUNK;
    int hi = lo + CHUNK; if (hi > E) hi = E;
    for (int e = lo + (int)threadIdx.x; e < hi; e += 256) {
        atomicAdd(&hd[__builtin_nontemporal_load(&dst[e]) >> BKSC], 1);
        atomicAdd(&hs[__builtin_nontemporal_load(&src[e]) >> BKSC], 1);
    }
    __syncthreads();
    for (int i = threadIdx.x; i < K; i += blockDim.x) {
        pbh_d[blockIdx.x * MAXKC + i] = hd[i];
        pbh_s[blockIdx.x * MAXKC + i] = hs[i];
        if (hd[i]) atomicAdd(&bhist_d[i], hd[i]);
        if (hs[i]) atomicAdd(&bhist_s[i], hs[i]);
    }
}

// parallel exclusive scan of both bucket-total arrays (K <= 128), single block
__global__ __launch_bounds__(128) void bucket_scan2(
        const int* __restrict__ bhist_d, int* __restrict__ bbase_d,
        int* __restrict__ bcursor_d, const int* __restrict__ bhist_s,
        int* __restrict__ bbase_s, int* __restrict__ bcursor_s, int K) {
    __shared__ int a[MAXKC];
    __shared__ int b[MAXKC];
    int t = threadIdx.x;
    int vd = (t < K) ? bhist_d[t] : 0;
    int vs = (t < K) ? bhist_s[t] : 0;
    a[t] = vd; b[t] = vs;
    __syncthreads();
    for (int off = 1; off < 128; off <<= 1) {
        int x = (t >= off) ? a[t - off] : 0;
        int y = (t >= off) ? b[t - off] : 0;
        __syncthreads();
        a[t] += x; b[t] += y;
        __syncthreads();
    }
    if (t < K) {
        int ed = a[t] - vd, es = b[t] - vs;
        bbase_d[t] = ed; bcursor_d[t] = ed;
        bbase_s[t] = es; bcursor_s[t] = es;
    }
    if (t == K - 1) { bbase_d[K] = a[t]; bbase_s[K] = b[t]; }
}

// one-pass counting place: per-block run reservation via ONE global atomicAdd
// per (block,bucket) using precomputed pbh counts, then scatter with LDS
// cursors. pairs = (src<<10|dst&1023) dst-sorted; ssort = src&1023 src-sorted.
__global__ __launch_bounds__(256) void bucket_place(const int* __restrict__ src,
        const int* __restrict__ dst, const int* __restrict__ pbh_d,
        const int* __restrict__ pbh_s, int* __restrict__ bcursor_d,
        int* __restrict__ bcursor_s, int* __restrict__ pairs,
        int* __restrict__ ssort, int E, int K) {
    __shared__ int cd[MAXKC];
    __shared__ int cs[MAXKC];
    for (int i = threadIdx.x; i < K; i += blockDim.x) {
        int nd = pbh_d[blockIdx.x * MAXKC + i];
        int ns = pbh_s[blockIdx.x * MAXKC + i];
        cd[i] = nd ? atomicAdd(&bcursor_d[i], nd) : 0;
        cs[i] = ns ? atomicAdd(&bcursor_s[i], ns) : 0;
    }
    __syncthreads();
    int lo = blockIdx.x * CHUNK;
    int hi = lo + CHUNK; if (hi > E) hi = E;
    for (int e = lo + (int)threadIdx.x; e < hi; e += 256) {
        int d = __builtin_nontemporal_load(&dst[e]);
        int s = __builtin_nontemporal_load(&src[e]);
        int pd = atomicAdd(&cd[d >> BKSC], 1);          // LDS atomic
        pairs[pd] = (s << BKSC) | (d & (BKC - 1));      // src<2^17 -> 27 bits
        int ps = atomicAdd(&cs[s >> BKSC], 1);
        ssort[ps] = s & (BKC - 1);
    }
}

// per-coarse-src-bucket LDS histogram over its ssort segment -> dout (f32).
// 1024 threads: h[] maps 1:1 to threads; edge loop ~32 iterations.
__global__ __launch_bounds__(1024) void bucket_outdeg(const int* __restrict__ bbase_s,
        const int* __restrict__ ssort, float* __restrict__ dout, int n_nodes) {
    __shared__ int h[BKC];
    int k = blockIdx.x;
    int t = threadIdx.x;
    int nbase = k << BKSC;
    int nrem = n_nodes - nbase; if (nrem > BKC) nrem = BKC;
    h[t] = 1;                                // self loop
    __syncthreads();
    int e0 = bbase_s[k], e1 = bbase_s[k + 1];
    for (int e = e0 + t; e < e1; e += 1024)
        atomicAdd(&h[__builtin_nontemporal_load(&ssort[e])], 1);
    __syncthreads();
    if (t < nrem) dout[nbase + t] = (float)(1.0 / sqrt((double)h[t]));
}

// FINE-granularity build over the COARSE-sorted pairs, 512 threads.
__global__ __launch_bounds__(512) void bucket_build(
        const int* __restrict__ bbase, const int* __restrict__ pairs,
        int* __restrict__ row_ptr, float* __restrict__ din,
        int* __restrict__ col, int n_nodes, int n_edges) {
    __shared__ int h[BKF];
    __shared__ int ts[BKF];
    __shared__ int red[512];
    __shared__ int ecol[ECAP];
    int nwg = gridDim.x;
    int xcd = blockIdx.x & 7;
    int loc = blockIdx.x >> 3;
    int q = nwg >> 3, r = nwg & 7;
    int k = ((xcd < r) ? xcd * (q + 1) : r * (q + 1) + (xcd - r) * q) + loc;
    int kc = k >> 2;             // coarse bucket
    int f  = k & 3;              // quarter within coarse bucket
    int t = threadIdx.x;
    int nbase = k << BKSF;
    int nrem = n_nodes - nbase; if (nrem > BKF) nrem = BKF;
    if (t < BKF) h[t] = 0;
    __syncthreads();
    int e0 = bbase[kc], e1 = bbase[kc + 1];
    int before = 0;
    for (int e = e0 + t; e < e1; e += 512) {
        int pk = pairs[e];                    // plain load: keep L2-cached for siblings
        int dl = pk & (BKC - 1);
        int fe = dl >> BKSF;
        if (fe == f) atomicAdd(&h[dl & (BKF - 1)], 1);
        else if (fe < f) ++before;
    }
    red[t] = before;
    __syncthreads();
    for (int off = 256; off > 0; off >>= 1) {
        if (t < off) red[t] += red[t + off];
        __syncthreads();
    }
    int fbase = e0 + red[0];                  // global base of this fine segment
    int c = (t < BKF) ? h[t] : 0;
    if (t < BKF) ts[t] = c;
    __syncthreads();
    for (int off = 1; off < BKF; off <<= 1) {
        int v = (t >= off && t < BKF) ? ts[t - off] : 0;
        __syncthreads();
        if (t < BKF) ts[t] += v;
        __syncthreads();
    }
    if (t < BKF) {
        int lx = ts[t] - c;                   // fine-local exclusive prefix
        if (t < nrem) {
            row_ptr[nbase + t] = fbase + lx;
            din[nbase + t] = (float)(1.0 / sqrt((double)(c + 1)));  // +1 self loop
        }
        h[t] = lx;                            // fine-local cursor into ecol
    }
    if (t == 0 && nbase + BKF >= n_nodes) row_ptr[n_nodes] = n_edges;
    __syncthreads();
    for (int e = e0 + t; e < e1; e += 512) {
        int pk = pairs[e];
        int dl = pk & (BKC - 1);
        if ((dl >> BKSF) == f) {
            int slot = atomicAdd(&h[dl & (BKF - 1)], 1);    // LDS atomic
            if (slot < ECAP) ecol[slot] = pk >> BKSC;
            else col[fbase + slot] = pk >> BKSC;            // overflow guard
        }
    }
    __syncthreads();
    int cnt = ts[BKF - 1];
    int lim = cnt < ECAP ? cnt : ECAP;
    for (int i = t; i < lim; i += 512)        // contiguous full-line stream-out
        col[fbase + i] = ecol[i];
}

// ---------------- layer kernels ----------------

// x0[n] = feat[n] * dout[n]
__global__ void compute_x0(const float* __restrict__ feat, const float* __restrict__ dout,
                           double* __restrict__ x0, int n) {
    int i = blockIdx.x * blockDim.x + threadIdx.x;
    if (i < n) x0[i] = (double)feat[i] * (double)dout[i];
}

// layer 0: g[n] = x0[n] + sum_{s in N(n)} x0[s]
__global__ __launch_bounds__(256) void layer_start(
        const double* __restrict__ x0, const int* __restrict__ row_ptr,
        const int* __restrict__ col, const float* __restrict__ din,
        const float* __restrict__ dout, const float* __restrict__ W,
        const float* __restrict__ b, float* __restrict__ xout, int n_nodes) {
    int n    = (blockIdx.x * blockDim.x + threadIdx.x) >> 6;
    int lane = threadIdx.x & 63;
    if (n >= n_nodes) return;
    double a = (lane == 0) ? x0[n] : 0.0;
    int e0 = row_ptr[n], e1 = row_ptr[n + 1];
    for (int e = e0 + lane; e < e1; e += 64)
        a += x0[__builtin_nontemporal_load(&col[e])];
#pragma unroll
    for (int off = 32; off > 0; off >>= 1)
        a += __shfl_xor(a, off, 64);
    if (lane < DH) {
        double v = a * (double)din[n] * (double)W[lane] + (double)b[lane];
        float r = fmaxf((float)v, 0.0f);
        xout[(long)n * DH + lane] = r * dout[n];
    }
}

// dense transform: y[n] = h'[n] @ W, written to 128B-padded rows (YP=32 floats,
// 20 used) so every gather touches exactly ONE cache line per edge-quarter-set.
__global__ __launch_bounds__(256) void transform(
        const float* __restrict__ h, const float* __restrict__ W,
        float4* __restrict__ y, int n_nodes) {
    __shared__ float Wl[DH * DH];
    for (int i = threadIdx.x; i < DH * DH; i += blockDim.x) Wl[i] = W[i];
    __syncthreads();
    int n = blockIdx.x * blockDim.x + threadIdx.x;
    if (n >= n_nodes) return;
    const float4* h4 = (const float4*)(h + (size_t)n * DH);
    float4 a0 = h4[0], a1 = h4[1], a2 = h4[2], a3 = h4[3], a4 = h4[4];
    float hv[DH] = {a0.x, a0.y, a0.z, a0.w, a1.x, a1.y, a1.z, a1.w,
                    a2.x, a2.y, a2.z, a2.w, a3.x, a3.y, a3.z, a3.w,
                    a4.x, a4.y, a4.z, a4.w};
    double acc[DH];
#pragma unroll
    for (int j = 0; j < DH; ++j) acc[j] = 0.0;
#pragma unroll
    for (int k = 0; k < DH; ++k) {
        double hk = (double)hv[k];
#pragma unroll
        for (int j = 0; j < DH; ++j)
            acc[j] += hk * (double)Wl[k * DH + j];
    }
    float4* yr = y + (size_t)n * (YP / 4);
    yr[0] = make_float4((float)acc[0],  (float)acc[1],  (float)acc[2],  (float)acc[3]);
    yr[1] = make_float4((float)acc[4],  (float)acc[5],  (float)acc[6],  (float)acc[7]);
    yr[2] = make_float4((float)acc[8],  (float)acc[9],  (float)acc[10], (float)acc[11]);
    yr[3] = make_float4((float)acc[12], (float)acc[13], (float)acc[14], (float)acc[15]);
    yr[4] = make_float4((float)acc[16], (float)acc[17], (float)acc[18], (float)acc[19]);
}

// gather+aggregate, TWO nodes per wave: doubles the in-flight gather loads
// (miss-level parallelism) against ~500cy remote-L2 latency — the measured
// bottleneck (R10: bytes-halving null, wave-doubling +34us => latency x MLP
// bound). Folds for A and B are independent shfl chains (same 4-round depth).
__global__ __launch_bounds__(256, 6) void gather_agg2(
        const float4* __restrict__ y, const int* __restrict__ row_ptr,
        const int* __restrict__ col, const float* __restrict__ din,
        const float* __restrict__ dout, const float* __restrict__ b,
        float* __restrict__ hout, int n_nodes, int mode) {
    int wv   = (blockIdx.x * blockDim.x + threadIdx.x) >> 6;   // global wave
    int lane = threadIdx.x & 63;
    int n0 = wv * 2;
    if (n0 >= n_nodes) return;
    int n1 = n0 + 1;
    bool has1 = (n1 < n_nodes);

    int ep = lane / 5;           // edge slot 0..12 (lanes 60..63 -> ep=12, inactive)
    int jq = lane - ep * 5;      // float4 quarter 0..4

    int ra = row_ptr[n0];
    int rb = row_ptr[n1];        // = end of A, start of B (CSR contiguity)
    int rc = has1 ? row_ptr[n1 + 1] : rb;

    // node A: slots against [ra, rb)
    int a0 = -1, a1 = -1, a2 = -1, a3 = -1;
    int b0 = -1, b1 = -1, b2 = -1, b3 = -1;
    if (ep < 12) {
        int p = ra + ep;
        if (p      < rb) a0 = __builtin_nontemporal_load(&col[p]);
        if (p + 12 < rb) a1 = __builtin_nontemporal_load(&col[p + 12]);
        if (p + 24 < rb) a2 = __builtin_nontemporal_load(&col[p + 24]);
        if (p + 36 < rb) a3 = __builtin_nontemporal_load(&col[p + 36]);
        int pq = rb + ep;
        if (pq      < rc) b0 = __builtin_nontemporal_load(&col[pq]);
        if (pq + 12 < rc) b1 = __builtin_nontemporal_load(&col[pq + 12]);
        if (pq + 24 < rc) b2 = __builtin_nontemporal_load(&col[pq + 24]);
        if (pq + 36 < rc) b3 = __builtin_nontemporal_load(&col[pq + 36]);
    }
    bool pa0 = a0 >= 0, pa1 = a1 >= 0, pa2 = a2 >= 0, pa3 = a3 >= 0;
    bool pb0 = b0 >= 0, pb1 = b1 >= 0, pb2 = b2 >= 0, pb3 = b3 >= 0;
    // 8 unconditional gathers in flight (invalid slots read L1-hot self row)
    float4 va0 = y[(size_t)(pa0 ? a0 : n0) * (YP / 4) + jq];
    float4 va1 = y[(size_t)(pa1 ? a1 : n0) * (YP / 4) + jq];
    float4 va2 = y[(size_t)(pa2 ? a2 : n0) * (YP / 4) + jq];
    float4 va3 = y[(size_t)(pa3 ? a3 : n0) * (YP / 4) + jq];
    float4 vb0 = y[(size_t)(pb0 ? b0 : n0) * (YP / 4) + jq];
    float4 vb1 = y[(size_t)(pb1 ? b1 : n0) * (YP / 4) + jq];
    float4 vb2 = y[(size_t)(pb2 ? b2 : n0) * (YP / 4) + jq];
    float4 vb3 = y[(size_t)(pb3 ? b3 : n0) * (YP / 4) + jq];

    float gA0 = 0.f, gA1 = 0.f, gA2 = 0.f, gA3 = 0.f;
    float gB0 = 0.f, gB1 = 0.f, gB2 = 0.f, gB3 = 0.f;
    if (ep == 0) {               // self loops handled by slot 0
        float4 v = y[(size_t)n0 * (YP / 4) + jq];
        gA0 = v.x; gA1 = v.y; gA2 = v.z; gA3 = v.w;
        if (has1) {
            float4 u = y[(size_t)n1 * (YP / 4) + jq];
            gB0 = u.x; gB1 = u.y; gB2 = u.z; gB3 = u.w;
        }
    }
    if (pa0) { gA0 += va0.x; gA1 += va0.y; gA2 += va0.z; gA3 += va0.w; }
    if (pa1) { gA0 += va1.x; gA1 += va1.y; gA2 += va1.z; gA3 += va1.w; }
    if (pa2) { gA0 += va2.x; gA1 += va2.y; gA2 += va2.z; gA3 += va2.w; }
    if (pa3) { gA0 += va3.x; gA1 += va3.y; gA2 += va3.z; gA3 += va3.w; }
    if (pb0) { gB0 += vb0.x; gB1 += vb0.y; gB2 += vb0.z; gB3 += vb0.w; }
    if (pb1) { gB0 += vb1.x; gB1 += vb1.y; gB2 += vb1.z; gB3 += vb1.w; }
    if (pb2) { gB0 += vb2.x; gB1 += vb2.y; gB2 += vb2.z; gB3 += vb2.w; }
    if (pb3) { gB0 += vb3.x; gB1 += vb3.y; gB2 += vb3.z; gB3 += vb3.w; }

    // rare tails: deg > 48 (wave-uniform branches)
    if (rb - ra > 48) {
        if (ep < 12) {
            for (int e = ra + 48 + ep; e < rb; e += 12) {
                int s = __builtin_nontemporal_load(&col[e]);
                float4 v = y[(size_t)s * (YP / 4) + jq];
                gA0 += v.x; gA1 += v.y; gA2 += v.z; gA3 += v.w;
            }
        }
    }
    if (rc - rb > 48) {
        if (ep < 12) {
            for (int e = rb + 48 + ep; e < rc; e += 12) {
                int s = __builtin_nontemporal_load(&col[e]);
                float4 v = y[(size_t)s * (YP / 4) + jq];
                gB0 += v.x; gB1 += v.y; gB2 += v.z; gB3 += v.w;
            }
        }
    }

    // fold 12 edge slots down to slot 0 (A and B interleaved, same depth)
#define FOLD(LIM, DELTA)                                                        \
    {                                                                           \
        int srcl = lane + DELTA; if (srcl > 63) srcl = lane;                    \
        float tA0 = __shfl(gA0, srcl, 64);                                      \
        float tA1 = __shfl(gA1, srcl, 64);                                      \
        float tA2 = __shfl(gA2, srcl, 64);                                      \
        float tA3 = __shfl(gA3, srcl, 64);                                      \
        float tB0 = __shfl(gB0, srcl, 64);                                      \
        float tB1 = __shfl(gB1, srcl, 64);                                      \
        float tB2 = __shfl(gB2, srcl, 64);                                      \
        float tB3 = __shfl(gB3, srcl, 64);                                      \
        if (ep < (LIM)) {                                                       \
            gA0 += tA0; gA1 += tA1; gA2 += tA2; gA3 += tA3;                     \
            gB0 += tB0; gB1 += tB1; gB2 += tB2; gB3 += tB3;                     \
        }                                                                       \
    }
    FOLD(4, 40)   // ep(0..3)  += ep+8
    FOLD(4, 20)   // ep(0..3)  += ep+4
    FOLD(2, 10)   // ep(0..1)  += ep+2
    FOLD(1, 5)    // ep(0)     += ep+1
#undef FOLD

    if (lane < 5) {
        float4 bb = ((const float4*)b)[lane];    // b row is 16B-aligned (80B stride)
        {
            float dn = din[n0];
            float o0 = gA0 * dn + bb.x;
            float o1 = gA1 * dn + bb.y;
            float o2 = gA2 * dn + bb.z;
            float o3 = gA3 * dn + bb.w;
            float4 w;
            if (mode == 0) {
                float dd = dout[n0];
                w.x = fmaxf(o0, 0.0f) * dd;
                w.y = fmaxf(o1, 0.0f) * dd;
                w.z = fmaxf(o2, 0.0f) * dd;
                w.w = fmaxf(o3, 0.0f) * dd;
            } else {
                w.x = o0; w.y = o1; w.z = o2; w.w = o3;
            }
            ((float4*)(hout + (size_t)n0 * DH))[lane] = w;
        }
        if (has1) {
            float dn = din[n1];
            float o0 = gB0 * dn + bb.x;
            float o1 = gB1 * dn + bb.y;
            float o2 = gB2 * dn + bb.z;
            float o3 = gB3 * dn + bb.w;
            float4 w;
            if (mode == 0) {
                float dd = dout[n1];
                w.x = fmaxf(o0, 0.0f) * dd;
                w.y = fmaxf(o1, 0.0f) * dd;
                w.z = fmaxf(o2, 0.0f) * dd;
                w.w = fmaxf(o3, 0.0f) * dd;
            } else {
                w.x = o0; w.y = o1; w.z = o2; w.w = o3;
            }
            ((float4*)(hout + (size_t)n1 * DH))[lane] = w;
        }
    }
}

// ---------------- launch ----------------

static inline size_t align256(size_t x) { return (x + 255) & ~(size_t)255; }

extern "C" void kernel_launch(void* const* d_in, const int* in_sizes, int n_in,
                              void* d_out, int out_size, void* d_ws, size_t ws_size,
                              hipStream_t stream) {
    const float* feat    = (const float*)d_in[0];
    const float* W_start = (const float*)d_in[1];
    const float* b_start = (const float*)d_in[2];
    const float* W_mid   = (const float*)d_in[3];
    const float* b_mid   = (const float*)d_in[4];
    const float* W_final = (const float*)d_in[5];
    const float* b_final = (const float*)d_in[6];
    const int*   src     = (const int*)d_in[7];
    const int*   dst     = (const int*)d_in[8];

    const int N = in_sizes[0];              // 100000
    const int E = in_sizes[7];              // 3200000
    const int L = in_sizes[3] / (DH * DH);  // 18 mid layers
    const int KC = (N + BKC - 1) / BKC;     // coarse buckets (98)
    const int KF = (N + BKF - 1) / BKF;     // fine buckets (391)
    const int NB = (E + CHUNK - 1) / CHUNK; // chunk blocks (782)

    // workspace carve-up
    char* p = (char*)d_ws;
    float* dout_f  = (float*)p;  p += align256(sizeof(float) * N);
    float* din_f   = (float*)p;  p += align256(sizeof(float) * N);
    double* x0     = (double*)p; p += align256(sizeof(double) * N);
    int* row_ptr   = (int*)p;    p += align256(sizeof(int) * (N + 1));
    int* bhist_d   = (int*)p;    p += align256(sizeof(int) * (MAXKC + 1));
    int* bhist_s   = (int*)p;    p += align256(sizeof(int) * (MAXKC + 1));
    int* bbase_d   = (int*)p;    p += align256(sizeof(int) * (MAXKC + 1));
    int* bbase_s   = (int*)p;    p += align256(sizeof(int) * (MAXKC + 1));
    int* bcursor_d = (int*)p;    p += align256(sizeof(int) * (MAXKC + 1));
    int* bcursor_s = (int*)p;    p += align256(sizeof(int) * (MAXKC + 1));
    int* pbh_d     = (int*)p;    p += align256(sizeof(int) * MAXNB * MAXKC);
    int* pbh_s     = (int*)p;    p += align256(sizeof(int) * MAXNB * MAXKC);
    int* col       = (int*)p;    p += align256(sizeof(int) * E);
    float* hbuf    = (float*)p;  p += align256(sizeof(float) * N * DH);
    float4* ypad   = (float4*)p; p += align256(sizeof(float) * N * YP);
    // pairs (E ints = 12.8MB) overlays hbuf+ypad (20.8MB); dead before layer_start
    int* pairs = (int*)hbuf;
    // ssort (E ints) aliases col: consumed by bucket_outdeg BEFORE bucket_build
    int* ssort = col;

    const int BT = 256;
    int grid_n   = (N + BT - 1) / BT;
    int grid_nw  = (N + 3) / 4;             // 1 node/wave kernels
    int grid_nw2 = (N + 7) / 8;             // 2 nodes/wave, 4 waves/block

    // ---- graph setup ----
    zero_bhist2<<<1, MAXKC, 0, stream>>>(bhist_d, bhist_s);
    bucket_hist2<<<NB, BT, 0, stream>>>(src, dst, pbh_d, pbh_s,
                                        bhist_d, bhist_s, E, KC);
    bucket_scan2<<<1, 128, 0, stream>>>(bhist_d, bbase_d, bcursor_d,
                                        bhist_s, bbase_s, bcursor_s, KC);
    bucket_place<<<NB, BT, 0, stream>>>(src, dst, pbh_d, pbh_s,
                                        bcursor_d, bcursor_s, pairs, ssort, E, KC);
    bucket_outdeg<<<KC, 1024, 0, stream>>>(bbase_s, ssort, dout_f, N);
    bucket_build<<<KF, 512, 0, stream>>>(bbase_d, pairs, row_ptr, din_f, col, N, E);

    // ---- layer 0 (scalar input) ----
    compute_x0<<<grid_n, BT, 0, stream>>>(feat, dout_f, x0, N);
    layer_start<<<grid_nw, BT, 0, stream>>>(x0, row_ptr, col, din_f, dout_f,
                                            W_start, b_start, hbuf, N);

    // ---- 18 mid layers: dense transform + gather-aggregate (2 nodes/wave) ----
    for (int l = 0; l < L; ++l) {
        transform<<<grid_n, BT, 0, stream>>>(hbuf, W_mid + (size_t)l * DH * DH, ypad, N);
        gather_agg2<<<grid_nw2, BT, 0, stream>>>(ypad, row_ptr, col, din_f, dout_f,
                                                 b_mid + (size_t)l * DH, hbuf, N, 0);
    }

    // ---- final layer: raw store to d_out ----
    transform<<<grid_n, BT, 0, stream>>>(hbuf, W_final, ypad, N);
    gather_agg2<<<grid_nw2, BT, 0, stream>>>(ypad, row_ptr, col, din_f, dout_f,
                                             b_final, (float*)d_out, N, 1);
}

// Round 14
// 1430.205 us; speedup vs baseline: 1.6047x; 1.0236x over previous
//
#include <hip/hip_runtime.h>

#define DH    20       // hidden width
#define YP    32       // padded y row (floats): 128B = exactly one cache line
#define BKSC  10       // log2 nodes per COARSE bucket (sort granularity)
#define BKC   1024     // nodes per coarse bucket
#define MAXKC 128      // max coarse buckets (N=100000 -> KC=98)
#define MAXNB 512      // max chunk blocks (E=3.2M/8192 -> 391)
#define BKSF  8        // log2 nodes per FINE bucket (build granularity)
#define BKF   256      // nodes per fine bucket
#define ECAP  10240    // LDS col-staging capacity per fine bucket (avg ~8.2K)
#define CHUNK 8192     // edges per hist/place block: 84-edge runs (336B) is the
                       // measured write-amp knee (4096 -> 98MB writes, R13)

// ---------------- setup kernels ----------------

__global__ void zero_bhist2(int* __restrict__ bhist_d, int* __restrict__ bhist_s) {
    int i = threadIdx.x;
    if (i < MAXKC) { bhist_d[i] = 0; bhist_s[i] = 0; }
}

// one read pass over src+dst; per-block histograms to pbh (global, coalesced)
// + bucket totals via ~98x2 global atomics per block (negligible)
__global__ __launch_bounds__(256) void bucket_hist2(const int* __restrict__ src,
        const int* __restrict__ dst, int* __restrict__ pbh_d,
        int* __restrict__ pbh_s, int* __restrict__ bhist_d,
        int* __restrict__ bhist_s, int E, int K) {
    __shared__ int hd[MAXKC];
    __shared__ int hs[MAXKC];
    for (int i = threadIdx.x; i < K; i += blockDim.x) { hd[i] = 0; hs[i] = 0; }
    __syncthreads();
    int lo = blockIdx.x * CHUNK;
    int hi = lo + CHUNK; if (hi > E) hi = E;
    for (int e = lo + (int)threadIdx.x; e < hi; e += 256) {
        atomicAdd(&hd[__builtin_nontemporal_load(&dst[e]) >> BKSC], 1);
        atomicAdd(&hs[__builtin_nontemporal_load(&src[e]) >> BKSC], 1);
    }
    __syncthreads();
    for (int i = threadIdx.x; i < K; i += blockDim.x) {
        pbh_d[blockIdx.x * MAXKC + i] = hd[i];
        pbh_s[blockIdx.x * MAXKC + i] = hs[i];
        if (hd[i]) atomicAdd(&bhist_d[i], hd[i]);
        if (hs[i]) atomicAdd(&bhist_s[i], hs[i]);
    }
}

// parallel exclusive scan of both bucket-total arrays (K <= 128), single block
__global__ __launch_bounds__(128) void bucket_scan2(
        const int* __restrict__ bhist_d, int* __restrict__ bbase_d,
        int* __restrict__ bcursor_d, const int* __restrict__ bhist_s,
        int* __restrict__ bbase_s, int* __restrict__ bcursor_s, int K) {
    __shared__ int a[MAXKC];
    __shared__ int b[MAXKC];
    int t = threadIdx.x;
    int vd = (t < K) ? bhist_d[t] : 0;
    int vs = (t < K) ? bhist_s[t] : 0;
    a[t] = vd; b[t] = vs;
    __syncthreads();
    for (int off = 1; off < 128; off <<= 1) {
        int x = (t >= off) ? a[t - off] : 0;
        int y = (t >= off) ? b[t - off] : 0;
        __syncthreads();
        a[t] += x; b[t] += y;
        __syncthreads();
    }
    if (t < K) {
        int ed = a[t] - vd, es = b[t] - vs;
        bbase_d[t] = ed; bcursor_d[t] = ed;
        bbase_s[t] = es; bcursor_s[t] = es;
    }
    if (t == K - 1) { bbase_d[K] = a[t]; bbase_s[K] = b[t]; }
}

// one-pass counting place: per-block run reservation via ONE global atomicAdd
// per (block,bucket) using precomputed pbh counts, then scatter with LDS
// cursors. pairs = (src<<10|dst&1023) dst-sorted; ssort = src&1023 src-sorted.
__global__ __launch_bounds__(256) void bucket_place(const int* __restrict__ src,
        const int* __restrict__ dst, const int* __restrict__ pbh_d,
        const int* __restrict__ pbh_s, int* __restrict__ bcursor_d,
        int* __restrict__ bcursor_s, int* __restrict__ pairs,
        int* __restrict__ ssort, int E, int K) {
    __shared__ int cd[MAXKC];
    __shared__ int cs[MAXKC];
    for (int i = threadIdx.x; i < K; i += blockDim.x) {
        int nd = pbh_d[blockIdx.x * MAXKC + i];
        int ns = pbh_s[blockIdx.x * MAXKC + i];
        cd[i] = nd ? atomicAdd(&bcursor_d[i], nd) : 0;
        cs[i] = ns ? atomicAdd(&bcursor_s[i], ns) : 0;
    }
    __syncthreads();
    int lo = blockIdx.x * CHUNK;
    int hi = lo + CHUNK; if (hi > E) hi = E;
    for (int e = lo + (int)threadIdx.x; e < hi; e += 256) {
        int d = __builtin_nontemporal_load(&dst[e]);
        int s = __builtin_nontemporal_load(&src[e]);
        int pd = atomicAdd(&cd[d >> BKSC], 1);          // LDS atomic
        pairs[pd] = (s << BKSC) | (d & (BKC - 1));      // src<2^17 -> 27 bits
        int ps = atomicAdd(&cs[s >> BKSC], 1);
        ssort[ps] = s & (BKC - 1);
    }
}

// per-coarse-src-bucket LDS histogram over its ssort segment -> dout (f32).
// 1024 threads: h[] maps 1:1 to threads; edge loop ~32 iterations.
__global__ __launch_bounds__(1024) void bucket_outdeg(const int* __restrict__ bbase_s,
        const int* __restrict__ ssort, float* __restrict__ dout, int n_nodes) {
    __shared__ int h[BKC];
    int k = blockIdx.x;
    int t = threadIdx.x;
    int nbase = k << BKSC;
    int nrem = n_nodes - nbase; if (nrem > BKC) nrem = BKC;
    h[t] = 1;                                // self loop
    __syncthreads();
    int e0 = bbase_s[k], e1 = bbase_s[k + 1];
    for (int e = e0 + t; e < e1; e += 1024)
        atomicAdd(&h[__builtin_nontemporal_load(&ssort[e])], 1);
    __syncthreads();
    if (t < nrem) dout[nbase + t] = (float)(1.0 / sqrt((double)h[t]));
}

// FINE-granularity build over the COARSE-sorted pairs, 512 threads.
__global__ __launch_bounds__(512) void bucket_build(
        const int* __restrict__ bbase, const int* __restrict__ pairs,
        int* __restrict__ row_ptr, float* __restrict__ din,
        int* __restrict__ col, int n_nodes, int n_edges) {
    __shared__ int h[BKF];
    __shared__ int ts[BKF];
    __shared__ int red[512];
    __shared__ int ecol[ECAP];
    int nwg = gridDim.x;
    int xcd = blockIdx.x & 7;
    int loc = blockIdx.x >> 3;
    int q = nwg >> 3, r = nwg & 7;
    int k = ((xcd < r) ? xcd * (q + 1) : r * (q + 1) + (xcd - r) * q) + loc;
    int kc = k >> 2;             // coarse bucket
    int f  = k & 3;              // quarter within coarse bucket
    int t = threadIdx.x;
    int nbase = k << BKSF;
    int nrem = n_nodes - nbase; if (nrem > BKF) nrem = BKF;
    if (t < BKF) h[t] = 0;
    __syncthreads();
    int e0 = bbase[kc], e1 = bbase[kc + 1];
    int before = 0;
    for (int e = e0 + t; e < e1; e += 512) {
        int pk = pairs[e];                    // plain load: keep L2-cached for siblings
        int dl = pk & (BKC - 1);
        int fe = dl >> BKSF;
        if (fe == f) atomicAdd(&h[dl & (BKF - 1)], 1);
        else if (fe < f) ++before;
    }
    red[t] = before;
    __syncthreads();
    for (int off = 256; off > 0; off >>= 1) {
        if (t < off) red[t] += red[t + off];
        __syncthreads();
    }
    int fbase = e0 + red[0];                  // global base of this fine segment
    int c = (t < BKF) ? h[t] : 0;
    if (t < BKF) ts[t] = c;
    __syncthreads();
    for (int off = 1; off < BKF; off <<= 1) {
        int v = (t >= off && t < BKF) ? ts[t - off] : 0;
        __syncthreads();
        if (t < BKF) ts[t] += v;
        __syncthreads();
    }
    if (t < BKF) {
        int lx = ts[t] - c;                   // fine-local exclusive prefix
        if (t < nrem) {
            row_ptr[nbase + t] = fbase + lx;
            din[nbase + t] = (float)(1.0 / sqrt((double)(c + 1)));  // +1 self loop
        }
        h[t] = lx;                            // fine-local cursor into ecol
    }
    if (t == 0 && nbase + BKF >= n_nodes) row_ptr[n_nodes] = n_edges;
    __syncthreads();
    for (int e = e0 + t; e < e1; e += 512) {
        int pk = pairs[e];
        int dl = pk & (BKC - 1);
        if ((dl >> BKSF) == f) {
            int slot = atomicAdd(&h[dl & (BKF - 1)], 1);    // LDS atomic
            if (slot < ECAP) ecol[slot] = pk >> BKSC;
            else col[fbase + slot] = pk >> BKSC;            // overflow guard
        }
    }
    __syncthreads();
    int cnt = ts[BKF - 1];
    int lim = cnt < ECAP ? cnt : ECAP;
    for (int i = t; i < lim; i += 512)        // contiguous full-line stream-out
        col[fbase + i] = ecol[i];
}

// ---------------- layer kernels ----------------

// x0[n] = feat[n] * dout[n]
__global__ void compute_x0(const float* __restrict__ feat, const float* __restrict__ dout,
                           double* __restrict__ x0, int n) {
    int i = blockIdx.x * blockDim.x + threadIdx.x;
    if (i < n) x0[i] = (double)feat[i] * (double)dout[i];
}

// layer 0: g[n] = x0[n] + sum_{s in N(n)} x0[s]
__global__ __launch_bounds__(256) void layer_start(
        const double* __restrict__ x0, const int* __restrict__ row_ptr,
        const int* __restrict__ col, const float* __restrict__ din,
        const float* __restrict__ dout, const float* __restrict__ W,
        const float* __restrict__ b, float* __restrict__ xout, int n_nodes) {
    int n    = (blockIdx.x * blockDim.x + threadIdx.x) >> 6;
    int lane = threadIdx.x & 63;
    if (n >= n_nodes) return;
    double a = (lane == 0) ? x0[n] : 0.0;
    int e0 = row_ptr[n], e1 = row_ptr[n + 1];
    for (int e = e0 + lane; e < e1; e += 64)
        a += x0[__builtin_nontemporal_load(&col[e])];
#pragma unroll
    for (int off = 32; off > 0; off >>= 1)
        a += __shfl_xor(a, off, 64);
    if (lane < DH) {
        double v = a * (double)din[n] * (double)W[lane] + (double)b[lane];
        float r = fmaxf((float)v, 0.0f);
        xout[(long)n * DH + lane] = r * dout[n];
    }
}

// dense transform: y[n] = h'[n] @ W, written to 128B-padded rows (YP=32 floats,
// 20 used) so every gather touches exactly ONE cache line per edge-quarter-set.
__global__ __launch_bounds__(256) void transform(
        const float* __restrict__ h, const float* __restrict__ W,
        float4* __restrict__ y, int n_nodes) {
    __shared__ float Wl[DH * DH];
    for (int i = threadIdx.x; i < DH * DH; i += blockDim.x) Wl[i] = W[i];
    __syncthreads();
    int n = blockIdx.x * blockDim.x + threadIdx.x;
    if (n >= n_nodes) return;
    const float4* h4 = (const float4*)(h + (size_t)n * DH);
    float4 a0 = h4[0], a1 = h4[1], a2 = h4[2], a3 = h4[3], a4 = h4[4];
    float hv[DH] = {a0.x, a0.y, a0.z, a0.w, a1.x, a1.y, a1.z, a1.w,
                    a2.x, a2.y, a2.z, a2.w, a3.x, a3.y, a3.z, a3.w,
                    a4.x, a4.y, a4.z, a4.w};
    double acc[DH];
#pragma unroll
    for (int j = 0; j < DH; ++j) acc[j] = 0.0;
#pragma unroll
    for (int k = 0; k < DH; ++k) {
        double hk = (double)hv[k];
#pragma unroll
        for (int j = 0; j < DH; ++j)
            acc[j] += hk * (double)Wl[k * DH + j];
    }
    float4* yr = y + (size_t)n * (YP / 4);
    yr[0] = make_float4((float)acc[0],  (float)acc[1],  (float)acc[2],  (float)acc[3]);
    yr[1] = make_float4((float)acc[4],  (float)acc[5],  (float)acc[6],  (float)acc[7]);
    yr[2] = make_float4((float)acc[8],  (float)acc[9],  (float)acc[10], (float)acc[11]);
    yr[3] = make_float4((float)acc[12], (float)acc[13], (float)acc[14], (float)acc[15]);
    yr[4] = make_float4((float)acc[16], (float)acc[17], (float)acc[18], (float)acc[19]);
}

// gather+aggregate, TWO nodes per wave (8 unconditional float4 gathers in
// flight). launch_bounds (256,4): the (256,6) bound capped VGPR at ~85 while
// ~90-100 are live here — possible scratch spill; (256,4) guarantees none.
__global__ __launch_bounds__(256, 4) void gather_agg2(
        const float4* __restrict__ y, const int* __restrict__ row_ptr,
        const int* __restrict__ col, const float* __restrict__ din,
        const float* __restrict__ dout, const float* __restrict__ b,
        float* __restrict__ hout, int n_nodes, int mode) {
    int wv   = (blockIdx.x * blockDim.x + threadIdx.x) >> 6;   // global wave
    int lane = threadIdx.x & 63;
    int n0 = wv * 2;
    if (n0 >= n_nodes) return;
    int n1 = n0 + 1;
    bool has1 = (n1 < n_nodes);

    int ep = lane / 5;           // edge slot 0..12 (lanes 60..63 -> ep=12, inactive)
    int jq = lane - ep * 5;      // float4 quarter 0..4

    int ra = row_ptr[n0];
    int rb = row_ptr[n1];        // = end of A, start of B (CSR contiguity)
    int rc = has1 ? row_ptr[n1 + 1] : rb;

    int a0 = -1, a1 = -1, a2 = -1, a3 = -1;
    int b0 = -1, b1 = -1, b2 = -1, b3 = -1;
    if (ep < 12) {
        int p = ra + ep;
        if (p      < rb) a0 = __builtin_nontemporal_load(&col[p]);
        if (p + 12 < rb) a1 = __builtin_nontemporal_load(&col[p + 12]);
        if (p + 24 < rb) a2 = __builtin_nontemporal_load(&col[p + 24]);
        if (p + 36 < rb) a3 = __builtin_nontemporal_load(&col[p + 36]);
        int pq = rb + ep;
        if (pq      < rc) b0 = __builtin_nontemporal_load(&col[pq]);
        if (pq + 12 < rc) b1 = __builtin_nontemporal_load(&col[pq + 12]);
        if (pq + 24 < rc) b2 = __builtin_nontemporal_load(&col[pq + 24]);
        if (pq + 36 < rc) b3 = __builtin_nontemporal_load(&col[pq + 36]);
    }
    bool pa0 = a0 >= 0, pa1 = a1 >= 0, pa2 = a2 >= 0, pa3 = a3 >= 0;
    bool pb0 = b0 >= 0, pb1 = b1 >= 0, pb2 = b2 >= 0, pb3 = b3 >= 0;
    // 8 unconditional gathers in flight (invalid slots read L1-hot self row)
    float4 va0 = y[(size_t)(pa0 ? a0 : n0) * (YP / 4) + jq];
    float4 va1 = y[(size_t)(pa1 ? a1 : n0) * (YP / 4) + jq];
    float4 va2 = y[(size_t)(pa2 ? a2 : n0) * (YP / 4) + jq];
    float4 va3 = y[(size_t)(pa3 ? a3 : n0) * (YP / 4) + jq];
    float4 vb0 = y[(size_t)(pb0 ? b0 : n0) * (YP / 4) + jq];
    float4 vb1 = y[(size_t)(pb1 ? b1 : n0) * (YP / 4) + jq];
    float4 vb2 = y[(size_t)(pb2 ? b2 : n0) * (YP / 4) + jq];
    float4 vb3 = y[(size_t)(pb3 ? b3 : n0) * (YP / 4) + jq];

    float gA0 = 0.f, gA1 = 0.f, gA2 = 0.f, gA3 = 0.f;
    float gB0 = 0.f, gB1 = 0.f, gB2 = 0.f, gB3 = 0.f;
    if (ep == 0) {               // self loops handled by slot 0
        float4 v = y[(size_t)n0 * (YP / 4) + jq];
        gA0 = v.x; gA1 = v.y; gA2 = v.z; gA3 = v.w;
        if (has1) {
            float4 u = y[(size_t)n1 * (YP / 4) + jq];
            gB0 = u.x; gB1 = u.y; gB2 = u.z; gB3 = u.w;
        }
    }
    if (pa0) { gA0 += va0.x; gA1 += va0.y; gA2 += va0.z; gA3 += va0.w; }
    if (pa1) { gA0 += va1.x; gA1 += va1.y; gA2 += va1.z; gA3 += va1.w; }
    if (pa2) { gA0 += va2.x; gA1 += va2.y; gA2 += va2.z; gA3 += va2.w; }
    if (pa3) { gA0 += va3.x; gA1 += va3.y; gA2 += va3.z; gA3 += va3.w; }
    if (pb0) { gB0 += vb0.x; gB1 += vb0.y; gB2 += vb0.z; gB3 += vb0.w; }
    if (pb1) { gB0 += vb1.x; gB1 += vb1.y; gB2 += vb1.z; gB3 += vb1.w; }
    if (pb2) { gB0 += vb2.x; gB1 += vb2.y; gB2 += vb2.z; gB3 += vb2.w; }
    if (pb3) { gB0 += vb3.x; gB1 += vb3.y; gB2 += vb3.z; gB3 += vb3.w; }

    // rare tails: deg > 48 (wave-uniform branches)
    if (rb - ra > 48) {
        if (ep < 12) {
            for (int e = ra + 48 + ep; e < rb; e += 12) {
                int s = __builtin_nontemporal_load(&col[e]);
                float4 v = y[(size_t)s * (YP / 4) + jq];
                gA0 += v.x; gA1 += v.y; gA2 += v.z; gA3 += v.w;
            }
        }
    }
    if (rc - rb > 48) {
        if (ep < 12) {
            for (int e = rb + 48 + ep; e < rc; e += 12) {
                int s = __builtin_nontemporal_load(&col[e]);
                float4 v = y[(size_t)s * (YP / 4) + jq];
                gB0 += v.x; gB1 += v.y; gB2 += v.z; gB3 += v.w;
            }
        }
    }

    // fold 12 edge slots down to slot 0 (A and B interleaved, same depth)
#define FOLD(LIM, DELTA)                                                        \
    {                                                                           \
        int srcl = lane + DELTA; if (srcl > 63) srcl = lane;                    \
        float tA0 = __shfl(gA0, srcl, 64);                                      \
        float tA1 = __shfl(gA1, srcl, 64);                                      \
        float tA2 = __shfl(gA2, srcl, 64);                                      \
        float tA3 = __shfl(gA3, srcl, 64);                                      \
        float tB0 = __shfl(gB0, srcl, 64);                                      \
        float tB1 = __shfl(gB1, srcl, 64);                                      \
        float tB2 = __shfl(gB2, srcl, 64);                                      \
        float tB3 = __shfl(gB3, srcl, 64);                                      \
        if (ep < (LIM)) {                                                       \
            gA0 += tA0; gA1 += tA1; gA2 += tA2; gA3 += tA3;                     \
            gB0 += tB0; gB1 += tB1; gB2 += tB2; gB3 += tB3;                     \
        }                                                                       \
    }
    FOLD(4, 40)   // ep(0..3)  += ep+8
    FOLD(4, 20)   // ep(0..3)  += ep+4
    FOLD(2, 10)   // ep(0..1)  += ep+2
    FOLD(1, 5)    // ep(0)     += ep+1
#undef FOLD

    if (lane < 5) {
        float4 bb = ((const float4*)b)[lane];    // b row is 16B-aligned (80B stride)
        {
            float dn = din[n0];
            float o0 = gA0 * dn + bb.x;
            float o1 = gA1 * dn + bb.y;
            float o2 = gA2 * dn + bb.z;
            float o3 = gA3 * dn + bb.w;
            float4 w;
            if (mode == 0) {
                float dd = dout[n0];
                w.x = fmaxf(o0, 0.0f) * dd;
                w.y = fmaxf(o1, 0.0f) * dd;
                w.z = fmaxf(o2, 0.0f) * dd;
                w.w = fmaxf(o3, 0.0f) * dd;
            } else {
                w.x = o0; w.y = o1; w.z = o2; w.w = o3;
            }
            ((float4*)(hout + (size_t)n0 * DH))[lane] = w;
        }
        if (has1) {
            float dn = din[n1];
            float o0 = gB0 * dn + bb.x;
            float o1 = gB1 * dn + bb.y;
            float o2 = gB2 * dn + bb.z;
            float o3 = gB3 * dn + bb.w;
            float4 w;
            if (mode == 0) {
                float dd = dout[n1];
                w.x = fmaxf(o0, 0.0f) * dd;
                w.y = fmaxf(o1, 0.0f) * dd;
                w.z = fmaxf(o2, 0.0f) * dd;
                w.w = fmaxf(o3, 0.0f) * dd;
            } else {
                w.x = o0; w.y = o1; w.z = o2; w.w = o3;
            }
            ((float4*)(hout + (size_t)n1 * DH))[lane] = w;
        }
    }
}

// ---------------- launch ----------------

static inline size_t align256(size_t x) { return (x + 255) & ~(size_t)255; }

extern "C" void kernel_launch(void* const* d_in, const int* in_sizes, int n_in,
                              void* d_out, int out_size, void* d_ws, size_t ws_size,
                              hipStream_t stream) {
    const float* feat    = (const float*)d_in[0];
    const float* W_start = (const float*)d_in[1];
    const float* b_start = (const float*)d_in[2];
    const float* W_mid   = (const float*)d_in[3];
    const float* b_mid   = (const float*)d_in[4];
    const float* W_final = (const float*)d_in[5];
    const float* b_final = (const float*)d_in[6];
    const int*   src     = (const int*)d_in[7];
    const int*   dst     = (const int*)d_in[8];

    const int N = in_sizes[0];              // 100000
    const int E = in_sizes[7];              // 3200000
    const int L = in_sizes[3] / (DH * DH);  // 18 mid layers
    const int KC = (N + BKC - 1) / BKC;     // coarse buckets (98)
    const int KF = (N + BKF - 1) / BKF;     // fine buckets (391)
    const int NB = (E + CHUNK - 1) / CHUNK; // chunk blocks (391)

    // workspace carve-up
    char* p = (char*)d_ws;
    float* dout_f  = (float*)p;  p += align256(sizeof(float) * N);
    float* din_f   = (float*)p;  p += align256(sizeof(float) * N);
    double* x0     = (double*)p; p += align256(sizeof(double) * N);
    int* row_ptr   = (int*)p;    p += align256(sizeof(int) * (N + 1));
    int* bhist_d   = (int*)p;    p += align256(sizeof(int) * (MAXKC + 1));
    int* bhist_s   = (int*)p;    p += align256(sizeof(int) * (MAXKC + 1));
    int* bbase_d   = (int*)p;    p += align256(sizeof(int) * (MAXKC + 1));
    int* bbase_s   = (int*)p;    p += align256(sizeof(int) * (MAXKC + 1));
    int* bcursor_d = (int*)p;    p += align256(sizeof(int) * (MAXKC + 1));
    int* bcursor_s = (int*)p;    p += align256(sizeof(int) * (MAXKC + 1));
    int* pbh_d     = (int*)p;    p += align256(sizeof(int) * MAXNB * MAXKC);
    int* pbh_s     = (int*)p;    p += align256(sizeof(int) * MAXNB * MAXKC);
    int* col       = (int*)p;    p += align256(sizeof(int) * E);
    float* hbuf    = (float*)p;  p += align256(sizeof(float) * N * DH);
    float4* ypad   = (float4*)p; p += align256(sizeof(float) * N * YP);
    // pairs (E ints = 12.8MB) overlays hbuf+ypad (20.8MB); dead before layer_start
    int* pairs = (int*)hbuf;
    // ssort (E ints) aliases col: consumed by bucket_outdeg BEFORE bucket_build
    int* ssort = col;

    const int BT = 256;
    int grid_n   = (N + BT - 1) / BT;
    int grid_nw  = (N + 3) / 4;             // 1 node/wave kernels
    int grid_nw2 = (N + 7) / 8;             // 2 nodes/wave, 4 waves/block

    // ---- graph setup ----
    zero_bhist2<<<1, MAXKC, 0, stream>>>(bhist_d, bhist_s);
    bucket_hist2<<<NB, BT, 0, stream>>>(src, dst, pbh_d, pbh_s,
                                        bhist_d, bhist_s, E, KC);
    bucket_scan2<<<1, 128, 0, stream>>>(bhist_d, bbase_d, bcursor_d,
                                        bhist_s, bbase_s, bcursor_s, KC);
    bucket_place<<<NB, BT, 0, stream>>>(src, dst, pbh_d, pbh_s,
                                        bcursor_d, bcursor_s, pairs, ssort, E, KC);
    bucket_outdeg<<<KC, 1024, 0, stream>>>(bbase_s, ssort, dout_f, N);
    bucket_build<<<KF, 512, 0, stream>>>(bbase_d, pairs, row_ptr, din_f, col, N, E);

    // ---- layer 0 (scalar input) ----
    compute_x0<<<grid_n, BT, 0, stream>>>(feat, dout_f, x0, N);
    layer_start<<<grid_nw, BT, 0, stream>>>(x0, row_ptr, col, din_f, dout_f,
                                            W_start, b_start, hbuf, N);

    // ---- 18 mid layers: dense transform + gather-aggregate (2 nodes/wave) ----
    for (int l = 0; l < L; ++l) {
        transform<<<grid_n, BT, 0, stream>>>(hbuf, W_mid + (size_t)l * DH * DH, ypad, N);
        gather_agg2<<<grid_nw2, BT, 0, stream>>>(ypad, row_ptr, col, din_f, dout_f,
                                                 b_mid + (size_t)l * DH, hbuf, N, 0);
    }

    // ---- final layer: raw store to d_out ----
    transform<<<grid_n, BT, 0, stream>>>(hbuf, W_final, ypad, N);
    gather_agg2<<<grid_nw2, BT, 0, stream>>>(ypad, row_ptr, col, din_f, dout_f,
                                             b_final, (float*)d_out, N, 1);
}

// Round 15
// 1407.256 us; speedup vs baseline: 1.6309x; 1.0163x over previous
//
#include <hip/hip_runtime.h>

#define DH    20       // hidden width
#define YP    32       // padded y row (floats): 128B = exactly one cache line
#define BKSC  10       // log2 nodes per COARSE bucket (sort granularity)
#define BKC   1024     // nodes per coarse bucket
#define MAXKC 128      // max coarse buckets (N=100000 -> KC=98)
#define MAXNB 512      // max chunk blocks (E=3.2M/8192 -> 391)
#define BKSF  8        // log2 nodes per FINE bucket (build granularity)
#define BKF   256      // nodes per fine bucket
#define ECAP  10240    // LDS col-staging capacity per fine bucket (avg ~8.2K)
#define CHUNK 8192     // edges per hist/place block: 84-edge runs (336B) is the
                       // measured write-amp knee (4096 -> 98MB writes, R13)

// ---------------- setup kernels ----------------

__global__ void zero_bhist2(int* __restrict__ bhist_d, int* __restrict__ bhist_s) {
    int i = threadIdx.x;
    if (i < MAXKC) { bhist_d[i] = 0; bhist_s[i] = 0; }
}

// one read pass over src+dst; per-block histograms to pbh (global, coalesced)
// + bucket totals via ~98x2 global atomics per block. 1024 threads: the
// per-thread serial chain drops 32->8 iterations (R14: place/hist were
// latency-bound at 12% occupancy, VALUBusy 1.8%).
__global__ __launch_bounds__(1024) void bucket_hist2(const int* __restrict__ src,
        const int* __restrict__ dst, int* __restrict__ pbh_d,
        int* __restrict__ pbh_s, int* __restrict__ bhist_d,
        int* __restrict__ bhist_s, int E, int K) {
    __shared__ int hd[MAXKC];
    __shared__ int hs[MAXKC];
    for (int i = threadIdx.x; i < K; i += blockDim.x) { hd[i] = 0; hs[i] = 0; }
    __syncthreads();
    int lo = blockIdx.x * CHUNK;
    int hi = lo + CHUNK; if (hi > E) hi = E;
    for (int e = lo + (int)threadIdx.x; e < hi; e += 1024) {
        atomicAdd(&hd[__builtin_nontemporal_load(&dst[e]) >> BKSC], 1);
        atomicAdd(&hs[__builtin_nontemporal_load(&src[e]) >> BKSC], 1);
    }
    __syncthreads();
    for (int i = threadIdx.x; i < K; i += blockDim.x) {
        pbh_d[blockIdx.x * MAXKC + i] = hd[i];
        pbh_s[blockIdx.x * MAXKC + i] = hs[i];
        if (hd[i]) atomicAdd(&bhist_d[i], hd[i]);
        if (hs[i]) atomicAdd(&bhist_s[i], hs[i]);
    }
}

// parallel exclusive scan of both bucket-total arrays (K <= 128), single block
__global__ __launch_bounds__(128) void bucket_scan2(
        const int* __restrict__ bhist_d, int* __restrict__ bbase_d,
        int* __restrict__ bcursor_d, const int* __restrict__ bhist_s,
        int* __restrict__ bbase_s, int* __restrict__ bcursor_s, int K) {
    __shared__ int a[MAXKC];
    __shared__ int b[MAXKC];
    int t = threadIdx.x;
    int vd = (t < K) ? bhist_d[t] : 0;
    int vs = (t < K) ? bhist_s[t] : 0;
    a[t] = vd; b[t] = vs;
    __syncthreads();
    for (int off = 1; off < 128; off <<= 1) {
        int x = (t >= off) ? a[t - off] : 0;
        int y = (t >= off) ? b[t - off] : 0;
        __syncthreads();
        a[t] += x; b[t] += y;
        __syncthreads();
    }
    if (t < K) {
        int ed = a[t] - vd, es = b[t] - vs;
        bbase_d[t] = ed; bcursor_d[t] = ed;
        bbase_s[t] = es; bcursor_s[t] = es;
    }
    if (t == K - 1) { bbase_d[K] = a[t]; bbase_s[K] = b[t]; }
}

// one-pass counting place: per-block run reservation via ONE global atomicAdd
// per (block,bucket) using precomputed pbh counts, then scatter with LDS
// cursors. 1024 threads (8-iteration chain); CHUNK stays 8192 so run lengths
// (and write amplification) are unchanged.
__global__ __launch_bounds__(1024) void bucket_place(const int* __restrict__ src,
        const int* __restrict__ dst, const int* __restrict__ pbh_d,
        const int* __restrict__ pbh_s, int* __restrict__ bcursor_d,
        int* __restrict__ bcursor_s, int* __restrict__ pairs,
        int* __restrict__ ssort, int E, int K) {
    __shared__ int cd[MAXKC];
    __shared__ int cs[MAXKC];
    for (int i = threadIdx.x; i < K; i += blockDim.x) {
        int nd = pbh_d[blockIdx.x * MAXKC + i];
        int ns = pbh_s[blockIdx.x * MAXKC + i];
        cd[i] = nd ? atomicAdd(&bcursor_d[i], nd) : 0;
        cs[i] = ns ? atomicAdd(&bcursor_s[i], ns) : 0;
    }
    __syncthreads();
    int lo = blockIdx.x * CHUNK;
    int hi = lo + CHUNK; if (hi > E) hi = E;
    for (int e = lo + (int)threadIdx.x; e < hi; e += 1024) {
        int d = __builtin_nontemporal_load(&dst[e]);
        int s = __builtin_nontemporal_load(&src[e]);
        int pd = atomicAdd(&cd[d >> BKSC], 1);          // LDS atomic
        pairs[pd] = (s << BKSC) | (d & (BKC - 1));      // src<2^17 -> 27 bits
        int ps = atomicAdd(&cs[s >> BKSC], 1);
        ssort[ps] = s & (BKC - 1);
    }
}

// per-coarse-src-bucket LDS histogram over its ssort segment -> dout (f32).
// 1024 threads: h[] maps 1:1 to threads; edge loop ~32 iterations.
__global__ __launch_bounds__(1024) void bucket_outdeg(const int* __restrict__ bbase_s,
        const int* __restrict__ ssort, float* __restrict__ dout, int n_nodes) {
    __shared__ int h[BKC];
    int k = blockIdx.x;
    int t = threadIdx.x;
    int nbase = k << BKSC;
    int nrem = n_nodes - nbase; if (nrem > BKC) nrem = BKC;
    h[t] = 1;                                // self loop
    __syncthreads();
    int e0 = bbase_s[k], e1 = bbase_s[k + 1];
    for (int e = e0 + t; e < e1; e += 1024)
        atomicAdd(&h[__builtin_nontemporal_load(&ssort[e])], 1);
    __syncthreads();
    if (t < nrem) dout[nbase + t] = (float)(1.0 / sqrt((double)h[t]));
}

// FINE-granularity build over the COARSE-sorted pairs, 512 threads.
__global__ __launch_bounds__(512) void bucket_build(
        const int* __restrict__ bbase, const int* __restrict__ pairs,
        int* __restrict__ row_ptr, float* __restrict__ din,
        int* __restrict__ col, int n_nodes, int n_edges) {
    __shared__ int h[BKF];
    __shared__ int ts[BKF];
    __shared__ int red[512];
    __shared__ int ecol[ECAP];
    int nwg = gridDim.x;
    int xcd = blockIdx.x & 7;
    int loc = blockIdx.x >> 3;
    int q = nwg >> 3, r = nwg & 7;
    int k = ((xcd < r) ? xcd * (q + 1) : r * (q + 1) + (xcd - r) * q) + loc;
    int kc = k >> 2;             // coarse bucket
    int f  = k & 3;              // quarter within coarse bucket
    int t = threadIdx.x;
    int nbase = k << BKSF;
    int nrem = n_nodes - nbase; if (nrem > BKF) nrem = BKF;
    if (t < BKF) h[t] = 0;
    __syncthreads();
    int e0 = bbase[kc], e1 = bbase[kc + 1];
    int before = 0;
    for (int e = e0 + t; e < e1; e += 512) {
        int pk = pairs[e];                    // plain load: keep L2-cached for siblings
        int dl = pk & (BKC - 1);
        int fe = dl >> BKSF;
        if (fe == f) atomicAdd(&h[dl & (BKF - 1)], 1);
        else if (fe < f) ++before;
    }
    red[t] = before;
    __syncthreads();
    for (int off = 256; off > 0; off >>= 1) {
        if (t < off) red[t] += red[t + off];
        __syncthreads();
    }
    int fbase = e0 + red[0];                  // global base of this fine segment
    int c = (t < BKF) ? h[t] : 0;
    if (t < BKF) ts[t] = c;
    __syncthreads();
    for (int off = 1; off < BKF; off <<= 1) {
        int v = (t >= off && t < BKF) ? ts[t - off] : 0;
        __syncthreads();
        if (t < BKF) ts[t] += v;
        __syncthreads();
    }
    if (t < BKF) {
        int lx = ts[t] - c;                   // fine-local exclusive prefix
        if (t < nrem) {
            row_ptr[nbase + t] = fbase + lx;
            din[nbase + t] = (float)(1.0 / sqrt((double)(c + 1)));  // +1 self loop
        }
        h[t] = lx;                            // fine-local cursor into ecol
    }
    if (t == 0 && nbase + BKF >= n_nodes) row_ptr[n_nodes] = n_edges;
    __syncthreads();
    for (int e = e0 + t; e < e1; e += 512) {
        int pk = pairs[e];
        int dl = pk & (BKC - 1);
        if ((dl >> BKSF) == f) {
            int slot = atomicAdd(&h[dl & (BKF - 1)], 1);    // LDS atomic
            if (slot < ECAP) ecol[slot] = pk >> BKSC;
            else col[fbase + slot] = pk >> BKSC;            // overflow guard
        }
    }
    __syncthreads();
    int cnt = ts[BKF - 1];
    int lim = cnt < ECAP ? cnt : ECAP;
    for (int i = t; i < lim; i += 512)        // contiguous full-line stream-out
        col[fbase + i] = ecol[i];
}

// ---------------- layer kernels ----------------

// x0[n] = feat[n] * dout[n]
__global__ void compute_x0(const float* __restrict__ feat, const float* __restrict__ dout,
                           double* __restrict__ x0, int n) {
    int i = blockIdx.x * blockDim.x + threadIdx.x;
    if (i < n) x0[i] = (double)feat[i] * (double)dout[i];
}

// layer 0: g[n] = x0[n] + sum_{s in N(n)} x0[s]
__global__ __launch_bounds__(256) void layer_start(
        const double* __restrict__ x0, const int* __restrict__ row_ptr,
        const int* __restrict__ col, const float* __restrict__ din,
        const float* __restrict__ dout, const float* __restrict__ W,
        const float* __restrict__ b, float* __restrict__ xout, int n_nodes) {
    int n    = (blockIdx.x * blockDim.x + threadIdx.x) >> 6;
    int lane = threadIdx.x & 63;
    if (n >= n_nodes) return;
    double a = (lane == 0) ? x0[n] : 0.0;
    int e0 = row_ptr[n], e1 = row_ptr[n + 1];
    for (int e = e0 + lane; e < e1; e += 64)
        a += x0[__builtin_nontemporal_load(&col[e])];
#pragma unroll
    for (int off = 32; off > 0; off >>= 1)
        a += __shfl_xor(a, off, 64);
    if (lane < DH) {
        double v = a * (double)din[n] * (double)W[lane] + (double)b[lane];
        float r = fmaxf((float)v, 0.0f);
        xout[(long)n * DH + lane] = r * dout[n];
    }
}

// dense transform: y[n] = h'[n] @ W, written to 128B-padded rows (YP=32 floats,
// 20 used) so every gather touches exactly ONE cache line per edge-quarter-set.
__global__ __launch_bounds__(256) void transform(
        const float* __restrict__ h, const float* __restrict__ W,
        float4* __restrict__ y, int n_nodes) {
    __shared__ float Wl[DH * DH];
    for (int i = threadIdx.x; i < DH * DH; i += blockDim.x) Wl[i] = W[i];
    __syncthreads();
    int n = blockIdx.x * blockDim.x + threadIdx.x;
    if (n >= n_nodes) return;
    const float4* h4 = (const float4*)(h + (size_t)n * DH);
    float4 a0 = h4[0], a1 = h4[1], a2 = h4[2], a3 = h4[3], a4 = h4[4];
    float hv[DH] = {a0.x, a0.y, a0.z, a0.w, a1.x, a1.y, a1.z, a1.w,
                    a2.x, a2.y, a2.z, a2.w, a3.x, a3.y, a3.z, a3.w,
                    a4.x, a4.y, a4.z, a4.w};
    double acc[DH];
#pragma unroll
    for (int j = 0; j < DH; ++j) acc[j] = 0.0;
#pragma unroll
    for (int k = 0; k < DH; ++k) {
        double hk = (double)hv[k];
#pragma unroll
        for (int j = 0; j < DH; ++j)
            acc[j] += hk * (double)Wl[k * DH + j];
    }
    float4* yr = y + (size_t)n * (YP / 4);
    yr[0] = make_float4((float)acc[0],  (float)acc[1],  (float)acc[2],  (float)acc[3]);
    yr[1] = make_float4((float)acc[4],  (float)acc[5],  (float)acc[6],  (float)acc[7]);
    yr[2] = make_float4((float)acc[8],  (float)acc[9],  (float)acc[10], (float)acc[11]);
    yr[3] = make_float4((float)acc[12], (float)acc[13], (float)acc[14], (float)acc[15]);
    yr[4] = make_float4((float)acc[16], (float)acc[17], (float)acc[18], (float)acc[19]);
}

// gather+aggregate, TWO nodes per wave (8 unconditional float4 gathers in
// flight), launch_bounds (256,4) — proven best config (R14).
__global__ __launch_bounds__(256, 4) void gather_agg2(
        const float4* __restrict__ y, const int* __restrict__ row_ptr,
        const int* __restrict__ col, const float* __restrict__ din,
        const float* __restrict__ dout, const float* __restrict__ b,
        float* __restrict__ hout, int n_nodes, int mode) {
    int wv   = (blockIdx.x * blockDim.x + threadIdx.x) >> 6;   // global wave
    int lane = threadIdx.x & 63;
    int n0 = wv * 2;
    if (n0 >= n_nodes) return;
    int n1 = n0 + 1;
    bool has1 = (n1 < n_nodes);

    int ep = lane / 5;           // edge slot 0..12 (lanes 60..63 -> ep=12, inactive)
    int jq = lane - ep * 5;      // float4 quarter 0..4

    int ra = row_ptr[n0];
    int rb = row_ptr[n1];        // = end of A, start of B (CSR contiguity)
    int rc = has1 ? row_ptr[n1 + 1] : rb;

    int a0 = -1, a1 = -1, a2 = -1, a3 = -1;
    int b0 = -1, b1 = -1, b2 = -1, b3 = -1;
    if (ep < 12) {
        int p = ra + ep;
        if (p      < rb) a0 = __builtin_nontemporal_load(&col[p]);
        if (p + 12 < rb) a1 = __builtin_nontemporal_load(&col[p + 12]);
        if (p + 24 < rb) a2 = __builtin_nontemporal_load(&col[p + 24]);
        if (p + 36 < rb) a3 = __builtin_nontemporal_load(&col[p + 36]);
        int pq = rb + ep;
        if (pq      < rc) b0 = __builtin_nontemporal_load(&col[pq]);
        if (pq + 12 < rc) b1 = __builtin_nontemporal_load(&col[pq + 12]);
        if (pq + 24 < rc) b2 = __builtin_nontemporal_load(&col[pq + 24]);
        if (pq + 36 < rc) b3 = __builtin_nontemporal_load(&col[pq + 36]);
    }
    bool pa0 = a0 >= 0, pa1 = a1 >= 0, pa2 = a2 >= 0, pa3 = a3 >= 0;
    bool pb0 = b0 >= 0, pb1 = b1 >= 0, pb2 = b2 >= 0, pb3 = b3 >= 0;
    // 8 unconditional gathers in flight (invalid slots read L1-hot self row)
    float4 va0 = y[(size_t)(pa0 ? a0 : n0) * (YP / 4) + jq];
    float4 va1 = y[(size_t)(pa1 ? a1 : n0) * (YP / 4) + jq];
    float4 va2 = y[(size_t)(pa2 ? a2 : n0) * (YP / 4) + jq];
    float4 va3 = y[(size_t)(pa3 ? a3 : n0) * (YP / 4) + jq];
    float4 vb0 = y[(size_t)(pb0 ? b0 : n0) * (YP / 4) + jq];
    float4 vb1 = y[(size_t)(pb1 ? b1 : n0) * (YP / 4) + jq];
    float4 vb2 = y[(size_t)(pb2 ? b2 : n0) * (YP / 4) + jq];
    float4 vb3 = y[(size_t)(pb3 ? b3 : n0) * (YP / 4) + jq];

    float gA0 = 0.f, gA1 = 0.f, gA2 = 0.f, gA3 = 0.f;
    float gB0 = 0.f, gB1 = 0.f, gB2 = 0.f, gB3 = 0.f;
    if (ep == 0) {               // self loops handled by slot 0
        float4 v = y[(size_t)n0 * (YP / 4) + jq];
        gA0 = v.x; gA1 = v.y; gA2 = v.z; gA3 = v.w;
        if (has1) {
            float4 u = y[(size_t)n1 * (YP / 4) + jq];
            gB0 = u.x; gB1 = u.y; gB2 = u.z; gB3 = u.w;
        }
    }
    if (pa0) { gA0 += va0.x; gA1 += va0.y; gA2 += va0.z; gA3 += va0.w; }
    if (pa1) { gA0 += va1.x; gA1 += va1.y; gA2 += va1.z; gA3 += va1.w; }
    if (pa2) { gA0 += va2.x; gA1 += va2.y; gA2 += va2.z; gA3 += va2.w; }
    if (pa3) { gA0 += va3.x; gA1 += va3.y; gA2 += va3.z; gA3 += va3.w; }
    if (pb0) { gB0 += vb0.x; gB1 += vb0.y; gB2 += vb0.z; gB3 += vb0.w; }
    if (pb1) { gB0 += vb1.x; gB1 += vb1.y; gB2 += vb1.z; gB3 += vb1.w; }
    if (pb2) { gB0 += vb2.x; gB1 += vb2.y; gB2 += vb2.z; gB3 += vb2.w; }
    if (pb3) { gB0 += vb3.x; gB1 += vb3.y; gB2 += vb3.z; gB3 += vb3.w; }

    // rare tails: deg > 48 (wave-uniform branches)
    if (rb - ra > 48) {
        if (ep < 12) {
            for (int e = ra + 48 + ep; e < rb; e += 12) {
                int s = __builtin_nontemporal_load(&col[e]);
                float4 v = y[(size_t)s * (YP / 4) + jq];
                gA0 += v.x; gA1 += v.y; gA2 += v.z; gA3 += v.w;
            }
        }
    }
    if (rc - rb > 48) {
        if (ep < 12) {
            for (int e = rb + 48 + ep; e < rc; e += 12) {
                int s = __builtin_nontemporal_load(&col[e]);
                float4 v = y[(size_t)s * (YP / 4) + jq];
                gB0 += v.x; gB1 += v.y; gB2 += v.z; gB3 += v.w;
            }
        }
    }

    // fold 12 edge slots down to slot 0 (A and B interleaved, same depth)
#define FOLD(LIM, DELTA)                                                        \
    {                                                                           \
        int srcl = lane + DELTA; if (srcl > 63) srcl = lane;                    \
        float tA0 = __shfl(gA0, srcl, 64);                                      \
        float tA1 = __shfl(gA1, srcl, 64);                                      \
        float tA2 = __shfl(gA2, srcl, 64);                                      \
        float tA3 = __shfl(gA3, srcl, 64);                                      \
        float tB0 = __shfl(gB0, srcl, 64);                                      \
        float tB1 = __shfl(gB1, srcl, 64);                                      \
        float tB2 = __shfl(gB2, srcl, 64);                                      \
        float tB3 = __shfl(gB3, srcl, 64);                                      \
        if (ep < (LIM)) {                                                       \
            gA0 += tA0; gA1 += tA1; gA2 += tA2; gA3 += tA3;                     \
            gB0 += tB0; gB1 += tB1; gB2 += tB2; gB3 += tB3;                     \
        }                                                                       \
    }
    FOLD(4, 40)   // ep(0..3)  += ep+8
    FOLD(4, 20)   // ep(0..3)  += ep+4
    FOLD(2, 10)   // ep(0..1)  += ep+2
    FOLD(1, 5)    // ep(0)     += ep+1
#undef FOLD

    if (lane < 5) {
        float4 bb = ((const float4*)b)[lane];    // b row is 16B-aligned (80B stride)
        {
            float dn = din[n0];
            float o0 = gA0 * dn + bb.x;
            float o1 = gA1 * dn + bb.y;
            float o2 = gA2 * dn + bb.z;
            float o3 = gA3 * dn + bb.w;
            float4 w;
            if (mode == 0) {
                float dd = dout[n0];
                w.x = fmaxf(o0, 0.0f) * dd;
                w.y = fmaxf(o1, 0.0f) * dd;
                w.z = fmaxf(o2, 0.0f) * dd;
                w.w = fmaxf(o3, 0.0f) * dd;
            } else {
                w.x = o0; w.y = o1; w.z = o2; w.w = o3;
            }
            ((float4*)(hout + (size_t)n0 * DH))[lane] = w;
        }
        if (has1) {
            float dn = din[n1];
            float o0 = gB0 * dn + bb.x;
            float o1 = gB1 * dn + bb.y;
            float o2 = gB2 * dn + bb.z;
            float o3 = gB3 * dn + bb.w;
            float4 w;
            if (mode == 0) {
                float dd = dout[n1];
                w.x = fmaxf(o0, 0.0f) * dd;
                w.y = fmaxf(o1, 0.0f) * dd;
                w.z = fmaxf(o2, 0.0f) * dd;
                w.w = fmaxf(o3, 0.0f) * dd;
            } else {
                w.x = o0; w.y = o1; w.z = o2; w.w = o3;
            }
            ((float4*)(hout + (size_t)n1 * DH))[lane] = w;
        }
    }
}

// ---------------- launch ----------------

static inline size_t align256(size_t x) { return (x + 255) & ~(size_t)255; }

extern "C" void kernel_launch(void* const* d_in, const int* in_sizes, int n_in,
                              void* d_out, int out_size, void* d_ws, size_t ws_size,
                              hipStream_t stream) {
    const float* feat    = (const float*)d_in[0];
    const float* W_start = (const float*)d_in[1];
    const float* b_start = (const float*)d_in[2];
    const float* W_mid   = (const float*)d_in[3];
    const float* b_mid   = (const float*)d_in[4];
    const float* W_final = (const float*)d_in[5];
    const float* b_final = (const float*)d_in[6];
    const int*   src     = (const int*)d_in[7];
    const int*   dst     = (const int*)d_in[8];

    const int N = in_sizes[0];              // 100000
    const int E = in_sizes[7];              // 3200000
    const int L = in_sizes[3] / (DH * DH);  // 18 mid layers
    const int KC = (N + BKC - 1) / BKC;     // coarse buckets (98)
    const int KF = (N + BKF - 1) / BKF;     // fine buckets (391)
    const int NB = (E + CHUNK - 1) / CHUNK; // chunk blocks (391)

    // workspace carve-up
    char* p = (char*)d_ws;
    float* dout_f  = (float*)p;  p += align256(sizeof(float) * N);
    float* din_f   = (float*)p;  p += align256(sizeof(float) * N);
    double* x0     = (double*)p; p += align256(sizeof(double) * N);
    int* row_ptr   = (int*)p;    p += align256(sizeof(int) * (N + 1));
    int* bhist_d   = (int*)p;    p += align256(sizeof(int) * (MAXKC + 1));
    int* bhist_s   = (int*)p;    p += align256(sizeof(int) * (MAXKC + 1));
    int* bbase_d   = (int*)p;    p += align256(sizeof(int) * (MAXKC + 1));
    int* bbase_s   = (int*)p;    p += align256(sizeof(int) * (MAXKC + 1));
    int* bcursor_d = (int*)p;    p += align256(sizeof(int) * (MAXKC + 1));
    int* bcursor_s = (int*)p;    p += align256(sizeof(int) * (MAXKC + 1));
    int* pbh_d     = (int*)p;    p += align256(sizeof(int) * MAXNB * MAXKC);
    int* pbh_s     = (int*)p;    p += align256(sizeof(int) * MAXNB * MAXKC);
    int* col       = (int*)p;    p += align256(sizeof(int) * E);
    float* hbuf    = (float*)p;  p += align256(sizeof(float) * N * DH);
    float4* ypad   = (float4*)p; p += align256(sizeof(float) * N * YP);
    // pairs (E ints = 12.8MB) overlays hbuf+ypad (20.8MB); dead before layer_start
    int* pairs = (int*)hbuf;
    // ssort (E ints) aliases col: consumed by bucket_outdeg BEFORE bucket_build
    int* ssort = col;

    const int BT = 256;
    int grid_n   = (N + BT - 1) / BT;
    int grid_nw  = (N + 3) / 4;             // 1 node/wave kernels
    int grid_nw2 = (N + 7) / 8;             // 2 nodes/wave, 4 waves/block

    // ---- graph setup ----
    zero_bhist2<<<1, MAXKC, 0, stream>>>(bhist_d, bhist_s);
    bucket_hist2<<<NB, 1024, 0, stream>>>(src, dst, pbh_d, pbh_s,
                                          bhist_d, bhist_s, E, KC);
    bucket_scan2<<<1, 128, 0, stream>>>(bhist_d, bbase_d, bcursor_d,
                                        bhist_s, bbase_s, bcursor_s, KC);
    bucket_place<<<NB, 1024, 0, stream>>>(src, dst, pbh_d, pbh_s,
                                          bcursor_d, bcursor_s, pairs, ssort, E, KC);
    bucket_outdeg<<<KC, 1024, 0, stream>>>(bbase_s, ssort, dout_f, N);
    bucket_build<<<KF, 512, 0, stream>>>(bbase_d, pairs, row_ptr, din_f, col, N, E);

    // ---- layer 0 (scalar input) ----
    compute_x0<<<grid_n, BT, 0, stream>>>(feat, dout_f, x0, N);
    layer_start<<<grid_nw, BT, 0, stream>>>(x0, row_ptr, col, din_f, dout_f,
                                            W_start, b_start, hbuf, N);

    // ---- 18 mid layers: dense transform + gather-aggregate (2 nodes/wave) ----
    for (int l = 0; l < L; ++l) {
        transform<<<grid_n, BT, 0, stream>>>(hbuf, W_mid + (size_t)l * DH * DH, ypad, N);
        gather_agg2<<<grid_nw2, BT, 0, stream>>>(ypad, row_ptr, col, din_f, dout_f,
                                                 b_mid + (size_t)l * DH, hbuf, N, 0);
    }

    // ---- final layer: raw store to d_out ----
    transform<<<grid_n, BT, 0, stream>>>(hbuf, W_final, ypad, N);
    gather_agg2<<<grid_nw2, BT, 0, stream>>>(ypad, row_ptr, col, din_f, dout_f,
                                             b_final, (float*)d_out, N, 1);
}